// Round 4
// baseline (1609.531 us; speedup 1.0000x reference)
//
#include <hip/hip_runtime.h>
#include <math.h>

// F=4, T=12, C=512, HID=256, OUT=12
#define NF 48
#define TT 12

typedef __bf16 v8bf __attribute__((ext_vector_type(8)));
typedef float v16f __attribute__((ext_vector_type(16)));

// direct global->LDS, 16B per lane; LDS dest must be wave-uniform (HW adds lane*16)
__device__ __forceinline__ void gld16(const void* g, void* l) {
  __builtin_amdgcn_global_load_lds(
      (const __attribute__((address_space(1))) void*)(uintptr_t)g,
      (__attribute__((address_space(3))) void*)(uintptr_t)l, 16, 0, 0);
}

// ---------------- small prep kernels ----------------

__global__ void k_init(float* __restrict__ deg, int* __restrict__ cnt, int n) {
  int i = blockIdx.x * blockDim.x + threadIdx.x;
  if (i < n) { deg[i] = 1.0f; cnt[i] = 0; cnt[n + i] = 0; }
}

__global__ void k_edge(const int* __restrict__ dst, const float* __restrict__ w,
                       float* __restrict__ deg, int* __restrict__ cnt, int e) {
  int i = blockIdx.x * blockDim.x + threadIdx.x;
  if (i < e) {
    int d = dst[i];
    atomicAdd(&deg[d], w[i]);
    atomicAdd(&cnt[d], 1);
  }
}

// ---------------- hierarchical scan (+ dinv fused) ----------------

__global__ void k_scan1(const int* __restrict__ cnt, int* __restrict__ pscan,
                        int* __restrict__ bsum, const float* __restrict__ deg,
                        float* __restrict__ dinv, int n) {
  __shared__ int s[256];
  int i = blockIdx.x * 256 + threadIdx.x;
  int v = (i < n) ? cnt[i] : 0;
  s[threadIdx.x] = v;
  __syncthreads();
  for (int off = 1; off < 256; off <<= 1) {
    int t = 0;
    if (threadIdx.x >= off) t = s[threadIdx.x - off];
    __syncthreads();
    s[threadIdx.x] += t;
    __syncthreads();
  }
  if (i < n) {
    pscan[i] = s[threadIdx.x] - v;
    dinv[i] = rsqrtf(fmaxf(deg[i], 1e-12f));
  }
  if (threadIdx.x == 255) bsum[blockIdx.x] = s[255];
}

__global__ void k_scan2(const int* __restrict__ bsum, int* __restrict__ bpre, int nb,
                        const float* __restrict__ att, float* __restrict__ probs) {
  if (blockIdx.x == 0 && threadIdx.x == 0) {
    int run = 0;
    for (int b = 0; b < nb; b++) { bpre[b] = run; run += bsum[b]; }
  }
  if (blockIdx.x == 0 && threadIdx.x == 64) {
    float m = -1e30f;
    for (int t = 0; t < TT; t++) m = fmaxf(m, att[t]);
    float e[TT], s = 0.f;
    for (int t = 0; t < TT; t++) { e[t] = expf(att[t] - m); s += e[t]; }
    for (int t = 0; t < TT; t++) probs[t] = e[t] / s;
  }
}

__global__ void k_scan3(const int* __restrict__ pscan, const int* __restrict__ bpre,
                        int* __restrict__ offs, int n, int e) {
  int i = blockIdx.x * blockDim.x + threadIdx.x;
  if (i < n) offs[i] = pscan[i] + bpre[i >> 8];
  if (i == 0) offs[n] = e;
}

__global__ void k_place(const int* __restrict__ src, const int* __restrict__ dst,
                        const float* __restrict__ w, const int* __restrict__ offs,
                        int* __restrict__ fill, int* __restrict__ csrc,
                        float* __restrict__ cw, int e) {
  int i = blockIdx.x * blockDim.x + threadIdx.x;
  if (i >= e) return;
  int d = dst[i];
  int p = offs[d] + atomicAdd(&fill[d], 1);
  csrc[p] = src[i];
  cw[p] = w[i];
}

__global__ void k_gather(const int* __restrict__ offs, const int* __restrict__ csrc,
                         const float* __restrict__ cw, const float* __restrict__ dinv,
                         const float* __restrict__ x, float* __restrict__ Y, int n) {
  int tg = blockIdx.x * blockDim.x + threadIdx.x;
  if (tg >= n * 12) return;
  int i = tg / 12, q = tg % 12;
  float di = dinv[i];
  const float4* x4 = (const float4*)x;
  float4 sv = x4[(size_t)i * 12 + q];
  float ax = di * sv.x, ay = di * sv.y, az = di * sv.z, aw = di * sv.w;
  int e1 = offs[i + 1];
  for (int e = offs[i]; e < e1; e++) {
    int s = csrc[e];
    float wv = cw[e] * dinv[s];
    float4 xv = x4[(size_t)s * 12 + q];
    ax = fmaf(wv, xv.x, ax); ay = fmaf(wv, xv.y, ay);
    az = fmaf(wv, xv.z, az); aw = fmaf(wv, xv.w, aw);
  }
  float4 o = make_float4(di * ax, di * ay, di * az, di * aw);
  ((float4*)Y)[(size_t)i * 12 + q] = o;
}

// ---------------- weight prep: LDS-tiled transpose into swizzled pack ----------------
// pack layout: [n/128][k/32][ row=n%128 ][ chunk(16B)^((row>>1)&3) ][ e ]
__device__ __forceinline__ size_t packIdx128(int n, int k) {
  int row = n & 127;
  int c = (k & 31) >> 3;
  return (size_t)(n >> 7) * (128 * 512) + (size_t)(k >> 5) * (128 * 32) +
         (size_t)row * 32 + (size_t)((c ^ ((row >> 1) & 3)) << 3) + (k & 7);
}

__global__ void k_pack3(const float* __restrict__ Wzl, const float* __restrict__ Wrl,
                        const float* __restrict__ Whl, const float* __restrict__ W1,
                        __bf16* __restrict__ WzrP, __bf16* __restrict__ WhP,
                        __bf16* __restrict__ W1P) {
  __shared__ __bf16 t[64][72];
  int modew = blockIdx.z;
  if (modew == 1 && blockIdx.x >= 8) return;
  if (modew == 2 && blockIdx.x >= 4) return;
  int n0 = blockIdx.x * 64, k0 = blockIdx.y * 64;
  __bf16* WT = (modew == 0) ? WzrP : (modew == 1) ? WhP : W1P;
#pragma unroll
  for (int p = 0; p < 4; p++) {
    int kk = p * 16 + (threadIdx.x >> 4);
    int nn = (threadIdx.x & 15) * 4;
    int n = n0 + nn, k = k0 + kk;
    float4 v;
    if (modew == 2) {
      v = *(const float4*)(W1 + (size_t)k * 256 + n);
    } else {
      const float* src = (modew == 1) ? Whl : Wzl;
      int nc = n;
      if (modew == 0 && n >= 512) { src = Wrl; nc = n - 512; }
      v = *(const float4*)(src + (size_t)(512 + k) * 512 + nc);
    }
    t[kk][nn + 0] = (__bf16)v.x; t[kk][nn + 1] = (__bf16)v.y;
    t[kk][nn + 2] = (__bf16)v.z; t[kk][nn + 3] = (__bf16)v.w;
  }
  __syncthreads();
#pragma unroll
  for (int u = 0; u < 2; u++) {
    int unit = threadIdx.x * 2 + u;
    int nl = unit >> 3, kg = unit & 7;
    v8bf o;
#pragma unroll
    for (int j = 0; j < 8; j++) o[j] = t[kg * 8 + j][nl];
    *(v8bf*)(WT + packIdx128(n0 + nl, k0 + kg * 8)) = o;
  }
}

__global__ void k_build_eff3(const float* __restrict__ Wzg, const float* __restrict__ Wzl,
                             const float* __restrict__ bzg, const float* __restrict__ bzl,
                             const float* __restrict__ Wrg, const float* __restrict__ Wrl,
                             const float* __restrict__ brg, const float* __restrict__ brl,
                             const float* __restrict__ Whg, const float* __restrict__ Whl,
                             const float* __restrict__ bhg, const float* __restrict__ bhl,
                             float* __restrict__ WzrE, float* __restrict__ bzrE,
                             float* __restrict__ WhE, float* __restrict__ bhE) {
  int idx = blockIdx.x * blockDim.x + threadIdx.x;
  if (idx >= 3 * 5 * 512) return;
  int seg = idx / 2560;
  int r = (idx % 2560) / 512, c = idx % 512;
  const float *Wg, *Wl, *bg, *bl;
  float *We, *be;
  int ostride, ooff;
  if (seg == 0) { Wg = Wzg; Wl = Wzl; bg = bzg; bl = bzl; We = WzrE; be = bzrE; ostride = 1024; ooff = 0; }
  else if (seg == 1) { Wg = Wrg; Wl = Wrl; bg = brg; bl = brl; We = WzrE; be = bzrE; ostride = 1024; ooff = 512; }
  else { Wg = Whg; Wl = Whl; bg = bhg; bl = bhl; We = WhE; be = bhE; ostride = 512; ooff = 0; }
  float s = 0.f;
  if (r < 4) {
    for (int k = 0; k < 512; k++) s += Wg[r * 512 + k] * Wl[k * 512 + c];
    We[r * ostride + ooff + c] = s;
  } else {
    for (int k = 0; k < 512; k++) s += bg[k] * Wl[k * 512 + c];
    be[ooff + c] = s + bl[c];
  }
}

__global__ void k_wy3(const float* __restrict__ WzrE, const float* __restrict__ bzrE,
                      const float* __restrict__ WhE, const float* __restrict__ bhE,
                      const float* __restrict__ b1,
                      __bf16* __restrict__ WyZR, __bf16* __restrict__ WyH,
                      __bf16* __restrict__ Wy1) {
  int idx = blockIdx.x * blockDim.x + threadIdx.x;
  const float* Weff; const float* beff; __bf16* out; int Nout, loc;
  if (idx < 1024 * 16) { Weff = WzrE; beff = bzrE; out = WyZR; Nout = 1024; loc = idx; }
  else if (idx < (1024 + 512) * 16) { Weff = WhE; beff = bhE; out = WyH; Nout = 512; loc = idx - 1024 * 16; }
  else if (idx < (1024 + 512 + 256) * 16) { Weff = nullptr; beff = b1; out = Wy1; Nout = 256; loc = idx - (1024 + 512) * 16; }
  else return;
  int n = loc >> 4, k = loc & 15;
  float v = 0.f;
  if (k < 4) v = Weff ? Weff[k * Nout + n] : 0.f;
  else if (k == 4) v = beff[n];
  out[(size_t)(n >> 7) * 2048 + (size_t)(n & 127) * 16 + k] = (__bf16)v;
}

__global__ void k_yat0(const float* __restrict__ Y,
                       const float* __restrict__ WzrE, const float* __restrict__ bzrE,
                       const float* __restrict__ WhE, const float* __restrict__ bhE,
                       __bf16* __restrict__ Ya, __bf16* __restrict__ H1, int n) {
  int idx = blockIdx.x * blockDim.x + threadIdx.x;
  int nt0 = n * 512;
  if (idx < nt0) {
    int i = idx >> 9, c = idx & 511;
    float y0 = Y[(size_t)i * NF + 0], y1 = Y[(size_t)i * NF + 12];
    float y2 = Y[(size_t)i * NF + 24], y3 = Y[(size_t)i * NF + 36];
    float pz = bzrE[c] + y0 * WzrE[c] + y1 * WzrE[1024 + c] +
               y2 * WzrE[2048 + c] + y3 * WzrE[3072 + c];
    float ph = bhE[c] + y0 * WhE[c] + y1 * WhE[512 + c] +
               y2 * WhE[1024 + c] + y3 * WhE[1536 + c];
    float z = 1.f / (1.f + expf(-pz));
    H1[idx] = (__bf16)((1.f - z) * tanhf(ph));
  } else {
    int r = idx - nt0;
    if (r >= TT * n * 16) return;
    int t = r / (n * 16);
    int loc = r % (n * 16);
    int nn = loc >> 4, k = loc & 15;
    float v = 0.f;
    if (k < 4) v = Y[(size_t)nn * NF + k * TT + t];
    else if (k == 4) v = 1.f;
    Ya[r] = (__bf16)v;
  }
}

// ---------------- cross-block sync primitives (rowblk-local dep graph) ----------------
// producer: __syncthreads (compiler drains vmcnt before s_barrier) -> release-agent
// fence (L2 writeback) -> system-scope add (visible at LLC).
// consumer: relaxed system-scope poll (bypasses caches, no inv churn) -> acquire-agent
// fence (invalidate stale clean L2/L1 lines) -> __syncthreads.
__device__ __forceinline__ void waitCtr(int* p, int target) {
  if (threadIdx.x == 0) {
    while (__hip_atomic_load(p, __ATOMIC_RELAXED, __HIP_MEMORY_SCOPE_SYSTEM) < target)
      __builtin_amdgcn_s_sleep(2);
    __builtin_amdgcn_fence(__ATOMIC_ACQUIRE, "agent");
  }
  __syncthreads();
}
__device__ __forceinline__ void postCtr(int* p) {
  __syncthreads();
  if (threadIdx.x == 0) {
    __builtin_amdgcn_fence(__ATOMIC_RELEASE, "agent");
    __hip_atomic_fetch_add(p, 1, __ATOMIC_RELAXED, __HIP_MEMORY_SCOPE_SYSTEM);
  }
}

// ---------------- 64x128 GEMM tile (R15 internals, mode 0/1 runtime) ----------------
__device__ __forceinline__ void gemm64(
    const int mode, const int row0, const int colblk,
    const __bf16* __restrict__ Agm, const __bf16* __restrict__ Bp,
    const __bf16* __restrict__ Hc, const __bf16* __restrict__ Zb,
    const __bf16* __restrict__ Ay, const __bf16* __restrict__ Wy,
    __bf16* __restrict__ Obf, __bf16* __restrict__ ObfR,
    const int M, __bf16* smem) {
  constexpr int BUFS = 6144;  // elems per LDS k-buffer: A 2048 + B 4096
  const int tid = threadIdx.x;
  const int lane = tid & 63, w = tid >> 6;
  const int wr = (w >> 1) * 32, wc = (w & 1) * 64;
  const int l31 = lane & 31, lh = lane >> 5;

  const int ar = tid >> 2, ac = tid & 3;
  const __bf16* At = Agm + (size_t)(row0 + ar) * 512 + ((ac ^ ((ar >> 1) & 3)) << 3);
  const __bf16* Bt = Bp + (size_t)colblk * (128 * 512);

  v16f acc[2];
#pragma unroll
  for (int j = 0; j < 2; j++)
#pragma unroll
    for (int q = 0; q < 16; q++) acc[j][q] = 0.f;

  auto stage = [&](int buf, int kt) {
    __bf16* base = smem + buf * BUFS;
    gld16(At + kt * 32, base + w * 512);
    const __bf16* bs = Bt + (size_t)kt * 4096 + (size_t)tid * 8;
    gld16(bs, base + 2048 + w * 512);
    gld16(bs + 2048, base + 4096 + w * 512);
  };
  auto stageY = [&]() {
    if (w < 2)
      gld16(Ay + (size_t)(row0 + (tid >> 1)) * 16 + (tid & 1) * 8,
            smem + 18432 + w * 512);
    gld16(Wy + (size_t)colblk * 2048 + (size_t)tid * 8, smem + 19456 + w * 512);
  };
  auto compute = [&](int buf) {
    const __bf16* base = smem + buf * BUFS;
    __builtin_amdgcn_s_setprio(1);
#pragma unroll
    for (int ks = 0; ks < 2; ks++) {
      int kc = ks * 2 + lh;
      int fr = wr + l31;
      v8bf a = *(const v8bf*)&base[fr * 32 + ((kc ^ ((fr >> 1) & 3)) << 3)];
#pragma unroll
      for (int ni = 0; ni < 2; ni++) {
        int fc = wc + ni * 32 + l31;
        v8bf b = *(const v8bf*)&base[2048 + fc * 32 + ((kc ^ ((fc >> 1) & 3)) << 3)];
        acc[ni] = __builtin_amdgcn_mfma_f32_32x32x16_bf16(a, b, acc[ni], 0, 0, 0);
      }
    }
    __builtin_amdgcn_s_setprio(0);
  };
  auto computeY = [&]() {
    const __bf16* ya = smem + 18432;
    const __bf16* yb = smem + 19456;
    v8bf a = *(const v8bf*)&ya[(wr + l31) * 16 + lh * 8];
#pragma unroll
    for (int ni = 0; ni < 2; ni++) {
      v8bf b = *(const v8bf*)&yb[(wc + ni * 32 + l31) * 16 + lh * 8];
      acc[ni] = __builtin_amdgcn_mfma_f32_32x32x16_bf16(a, b, acc[ni], 0, 0, 0);
    }
  };

  stageY();
  stage(0, 0);
  stage(1, 1);
#pragma unroll
  for (int kt = 0; kt < 16; kt++) {
    if (kt < 15)
      asm volatile("s_waitcnt vmcnt(3) lgkmcnt(0)\n\ts_barrier" ::: "memory");
    else
      asm volatile("s_waitcnt vmcnt(0) lgkmcnt(0)\n\ts_barrier" ::: "memory");
    if (kt < 14) stage((kt + 2) % 3, kt + 2);
    compute(kt % 3);
  }
  computeY();
  __syncthreads();  // before reusing smem as output stage

  // ---- epilogue. C layout (32x32): col=lane&31, row=(reg&3)+8*(reg>>2)+4*lh
  if (mode == 0) {
#pragma unroll
    for (int ni = 0; ni < 2; ni++) {
      int cl = wc + ni * 32 + l31;
#pragma unroll
      for (int reg = 0; reg < 16; reg++) {
        int lr = wr + (reg & 3) + ((reg >> 2) << 3) + (lh << 2);
        smem[lr * 128 + cl] = (__bf16)(1.f / (1.f + expf(-acc[ni][reg])));
      }
    }
    __syncthreads();
    int row = tid >> 2, seg = (tid & 3) * 32;
    int rg = row0 + row;
    if (rg < M) {
      int cof = (colblk & 3) * 128;
      if (colblk < 4) {  // z -> Obf, raw sigmoid
#pragma unroll
        for (int q = 0; q < 4; q++) {
          uint4 v = *(const uint4*)&smem[row * 128 + seg + q * 8];
          *(uint4*)(Obf + (size_t)rg * 512 + cof + seg + q * 8) = v;
        }
      } else {  // r -> ObfR, fused r*H (Agm holds H for these rows)
#pragma unroll
        for (int q = 0; q < 4; q++) {
          v8bf r8 = *(const v8bf*)&smem[row * 128 + seg + q * 8];
          v8bf h8 = *(const v8bf*)(Agm + (size_t)rg * 512 + cof + seg + q * 8);
          v8bf o;
#pragma unroll
          for (int j = 0; j < 8; j++) o[j] = (__bf16)((float)r8[j] * (float)h8[j]);
          *(v8bf*)(ObfR + (size_t)rg * 512 + cof + seg + q * 8) = o;
        }
      }
    }
  } else {  // mode 1: two 32-row passes; fp32 ht region = 32x128 = 16 KB
    float* sF = (float*)smem;
#pragma unroll
    for (int h = 0; h < 2; h++) {
      if ((w >> 1) == h) {
#pragma unroll
        for (int ni = 0; ni < 2; ni++) {
          int cl = wc + ni * 32 + l31;
#pragma unroll
          for (int reg = 0; reg < 16; reg++) {
            int lr = (reg & 3) + ((reg >> 2) << 3) + (lh << 2);
            sF[lr * 128 + cl] = tanhf(acc[ni][reg]);
          }
        }
      }
      __syncthreads();
      int row = tid >> 3, seg = (tid & 7) * 16;
      int rg = row0 + h * 32 + row;
      if (rg < M) {
        int cg0 = colblk * 128 + seg;
#pragma unroll
        for (int q = 0; q < 2; q++) {
          v8bf z8 = *(const v8bf*)(Zb + (size_t)rg * 512 + cg0 + q * 8);
          v8bf h8 = *(const v8bf*)(Hc + (size_t)rg * 512 + cg0 + q * 8);
          v8bf o;
#pragma unroll
          for (int j = 0; j < 8; j++) {
            float z = (float)z8[j];
            float ht = sF[row * 128 + seg + q * 8 + j];
            o[j] = (__bf16)(z * (float)h8[j] + (1.f - z) * ht);
          }
          *(v8bf*)(Obf + (size_t)rg * 512 + cg0 + q * 8) = o;
        }
      }
      if (h == 0) __syncthreads();
    }
  }
}

// ---------------- persistent t-loop: all 11 timesteps, rowblk-local flags ----------------
// Grid MUST be 768 = 256 CU x 3 blocks (LDS 3x42KB=126<=160KB; launch_bounds caps VGPR)
// so all blocks are co-resident -> spin-wait protocol is deadlock-free (jobs executed
// per-block in increasing (t,u); every dependency sits at an earlier (t,u)).
__global__ __launch_bounds__(256, 3) void k_tloop(
    __bf16* __restrict__ hist, __bf16* __restrict__ Zbf, __bf16* __restrict__ Rbf,
    const __bf16* __restrict__ WzrP, const __bf16* __restrict__ WhP,
    const __bf16* __restrict__ WyZR, const __bf16* __restrict__ WyH,
    const __bf16* __restrict__ Ya, int* __restrict__ ctr0, int* __restrict__ ctr1,
    int M, int RB) {
  // 3 k-buffers (18432) + Y region: Ay 1024 + Wy 2048 = 21504 elems = 42 KB
  __shared__ __bf16 smem[21504];
  const size_t S = (size_t)M * 512;
  const int J0 = RB * 8, JT = RB * 12;
  for (int t = 1; t < TT; t++) {
    const __bf16* Hbt = hist + (size_t)t * S;
    __bf16* Hbn = hist + (size_t)(t + 1) * S;
    const __bf16* Yat = Ya + (size_t)t * (size_t)M * 16;
    for (int u = blockIdx.x; u < JT; u += gridDim.x) {
      if (u < J0) {  // MODE0: A=H_t -> z (Zbf), r*H (Rbf)
        int r = u >> 3, c = u & 7;
        if (t > 1) waitCtr(&ctr1[(t - 1) * RB + r], 4);  // H_t rows r ready
        gemm64(0, r * 64, c, Hbt, WzrP, nullptr, nullptr, Yat, WyZR, Zbf, Rbf, M, smem);
        postCtr(&ctr0[t * RB + r]);
      } else {  // MODE1: A=r*H -> H_{t+1}
        int v = u - J0;
        int r = v >> 2, c = v & 3;
        waitCtr(&ctr0[t * RB + r], 8);  // Rbf rows r (full width) + Zbf rows r ready
        gemm64(1, r * 64, c, Rbf, WhP, Hbt, Zbf, Yat, WyH, Hbn, nullptr, M, smem);
        postCtr(&ctr1[t * RB + r]);
      }
    }
  }
}

// ---------------- MODE2 head GEMM (unchanged R15 template, only <2> used) ----------------
template <int MODE>
__global__ __launch_bounds__(256, 4) void k_mm(
    const __bf16* __restrict__ Agm, const __bf16* __restrict__ Bp,
    const __bf16* __restrict__ Hc, const __bf16* __restrict__ Zbf,
    const __bf16* __restrict__ Ay, const __bf16* __restrict__ Wy,
    float* __restrict__ Ofp, __bf16* __restrict__ Obf, __bf16* __restrict__ ObfR,
    int M, int RB) {
  constexpr int BUFS = 6144;
  __shared__ __bf16 smem[21504];

  const int RBX = (RB + 7) >> 3;
  {
    int xcd = blockIdx.x & 7;
    int idx = blockIdx.x >> 3;
    int rowblk = xcd * RBX + idx % RBX;
    int colblk = idx / RBX;
    if (rowblk >= RB) return;

    const int row0 = rowblk * 64;
    const int tid = threadIdx.x;
    const int lane = tid & 63, w = tid >> 6;
    const int wr = (w >> 1) * 32, wc = (w & 1) * 64;
    const int l31 = lane & 31, lh = lane >> 5;

    const int ar = tid >> 2, ac = tid & 3;
    const __bf16* At = Agm + (size_t)(row0 + ar) * 512 + ((ac ^ ((ar >> 1) & 3)) << 3);
    const __bf16* Bt = Bp + (size_t)colblk * (128 * 512);

    v16f acc[2];
#pragma unroll
    for (int j = 0; j < 2; j++)
#pragma unroll
      for (int q = 0; q < 16; q++) acc[j][q] = 0.f;

    auto stage = [&](int buf, int kt) {
      __bf16* base = smem + buf * BUFS;
      gld16(At + kt * 32, base + w * 512);
      const __bf16* bs = Bt + (size_t)kt * 4096 + (size_t)tid * 8;
      gld16(bs, base + 2048 + w * 512);
      gld16(bs + 2048, base + 4096 + w * 512);
    };
    auto stageY = [&]() {
      if (w < 2)
        gld16(Ay + (size_t)(row0 + (tid >> 1)) * 16 + (tid & 1) * 8,
              smem + 18432 + w * 512);
      gld16(Wy + (size_t)colblk * 2048 + (size_t)tid * 8, smem + 19456 + w * 512);
    };
    auto compute = [&](int buf) {
      const __bf16* base = smem + buf * BUFS;
      __builtin_amdgcn_s_setprio(1);
#pragma unroll
      for (int ks = 0; ks < 2; ks++) {
        int kc = ks * 2 + lh;
        int fr = wr + l31;
        v8bf a = *(const v8bf*)&base[fr * 32 + ((kc ^ ((fr >> 1) & 3)) << 3)];
#pragma unroll
        for (int ni = 0; ni < 2; ni++) {
          int fc = wc + ni * 32 + l31;
          v8bf b = *(const v8bf*)&base[2048 + fc * 32 + ((kc ^ ((fc >> 1) & 3)) << 3)];
          acc[ni] = __builtin_amdgcn_mfma_f32_32x32x16_bf16(a, b, acc[ni], 0, 0, 0);
        }
      }
      __builtin_amdgcn_s_setprio(0);
    };
    auto computeY = [&]() {
      const __bf16* ya = smem + 18432;
      const __bf16* yb = smem + 19456;
      v8bf a = *(const v8bf*)&ya[(wr + l31) * 16 + lh * 8];
#pragma unroll
      for (int ni = 0; ni < 2; ni++) {
        v8bf b = *(const v8bf*)&yb[(wc + ni * 32 + l31) * 16 + lh * 8];
        acc[ni] = __builtin_amdgcn_mfma_f32_32x32x16_bf16(a, b, acc[ni], 0, 0, 0);
      }
    };

    stageY();
    stage(0, 0);
    stage(1, 1);
#pragma unroll
    for (int kt = 0; kt < 16; kt++) {
      if (kt < 15)
        asm volatile("s_waitcnt vmcnt(3) lgkmcnt(0)\n\ts_barrier" ::: "memory");
      else
        asm volatile("s_waitcnt vmcnt(0) lgkmcnt(0)\n\ts_barrier" ::: "memory");
      if (kt < 14) stage((kt + 2) % 3, kt + 2);
      compute(kt % 3);
    }
    computeY();
    __syncthreads();

    if constexpr (MODE == 2) {
#pragma unroll
      for (int ni = 0; ni < 2; ni++) {
        int cl = wc + ni * 32 + l31;
#pragma unroll
        for (int reg = 0; reg < 16; reg++) {
          int rg = row0 + wr + (reg & 3) + ((reg >> 2) << 3) + (lh << 2);
          if (rg >= M) continue;
          Ofp[(size_t)rg * 256 + colblk * 128 + cl] = fmaxf(acc[ni][reg], 0.f);
        }
      }
    }
  }
}

// acc[i,c] = sum_t probs[t] * hist[t+1][i,c];  accRelu = bf16(relu(acc))
__global__ void k_acc(const __bf16* __restrict__ hist, const float* __restrict__ probs,
                      float* __restrict__ acc, __bf16* __restrict__ accRelu, int n) {
  int idx = blockIdx.x * blockDim.x + threadIdx.x;
  if (idx >= n * 64) return;
  size_t off = (size_t)idx * 8;
  size_t S = (size_t)n * 512;
  float s[8] = {0, 0, 0, 0, 0, 0, 0, 0};
#pragma unroll
  for (int t = 0; t < TT; t++) {
    float p = probs[t];
    v8bf h = *(const v8bf*)(hist + (size_t)(t + 1) * S + off);
#pragma unroll
    for (int j = 0; j < 8; j++) s[j] = fmaf(p, (float)h[j], s[j]);
  }
  *(float4*)(acc + off) = make_float4(s[0], s[1], s[2], s[3]);
  *(float4*)(acc + off + 4) = make_float4(s[4], s[5], s[6], s[7]);
  v8bf rl;
#pragma unroll
  for (int j = 0; j < 8; j++) rl[j] = (__bf16)fmaxf(s[j], 0.f);
  *(v8bf*)(accRelu + off) = rl;
}

__global__ void k_head2(const float* __restrict__ T1, const float* __restrict__ W2,
                        const float* __restrict__ b2, float* __restrict__ out0, int M) {
  int idx = blockIdx.x * blockDim.x + threadIdx.x;
  if (idx >= M * 12) return;
  int i = idx / 12, c = idx % 12;
  const float* tr = T1 + (size_t)i * 256;
  float s = b2[c];
  for (int k = 0; k < 256; k++) s = fmaf(tr[k], W2[k * 12 + c], s);
  out0[idx] = s;
}

// ---------------- launch ----------------

extern "C" void kernel_launch(void* const* d_in, const int* in_sizes, int n_in,
                              void* d_out, int out_size, void* d_ws, size_t ws_size,
                              hipStream_t stream) {
  const float* x   = (const float*)d_in[0];
  const int*   ei  = (const int*)d_in[1];
  const float* ea  = (const float*)d_in[2];
  const float* att = (const float*)d_in[3];
  const float* Wzg = (const float*)d_in[4];  const float* bzg = (const float*)d_in[5];
  const float* Wzl = (const float*)d_in[6];  const float* bzl = (const float*)d_in[7];
  const float* Wrg = (const float*)d_in[8];  const float* brg = (const float*)d_in[9];
  const float* Wrl = (const float*)d_in[10]; const float* brl = (const float*)d_in[11];
  const float* Whg = (const float*)d_in[12]; const float* bhg = (const float*)d_in[13];
  const float* Whl = (const float*)d_in[14]; const float* bhl = (const float*)d_in[15];
  const float* W1  = (const float*)d_in[16]; const float* b1  = (const float*)d_in[17];
  const float* W2  = (const float*)d_in[18]; const float* b2  = (const float*)d_in[19];

  const int N = in_sizes[0] / NF;
  const int E = in_sizes[1] / 2;
  const int* srcI = ei;
  const int* dstI = ei + E;

  float* out0 = (float*)d_out;                   // [N,12]
  float* accO = (float*)d_out + (size_t)N * 12;  // [N,512] = H_accum (output 1)

  char* wp = (char*)d_ws;
  auto carve = [&](size_t bytes) -> void* {
    void* p = (void*)wp;
    wp += (bytes + 255) & ~(size_t)255;
    return p;
  };
  float*  deg     = (float*)carve((size_t)N * 4);
  float*  dinv    = (float*)carve((size_t)N * 4);
  float*  probs   = (float*)carve(64);
  float*  Y       = (float*)carve((size_t)N * NF * 4);
  __bf16* WzrP    = (__bf16*)carve((size_t)1024 * 512 * 2);
  __bf16* WhP     = (__bf16*)carve((size_t)512 * 512 * 2);
  __bf16* W1P     = (__bf16*)carve((size_t)256 * 512 * 2);
  float*  Wzr_eff = (float*)carve((size_t)4 * 1024 * 4);
  float*  bzr_eff = (float*)carve((size_t)1024 * 4);
  float*  Wh_eff  = (float*)carve((size_t)4 * 512 * 4);
  float*  bh_eff  = (float*)carve((size_t)512 * 4);
  __bf16* hist    = (__bf16*)carve((size_t)(TT + 1) * N * 512 * 2);  // H_0..H_12 bf16
  __bf16* Zbf     = (__bf16*)carve((size_t)N * 512 * 2);
  __bf16* Rbf     = (__bf16*)carve((size_t)N * 512 * 2);  // holds r*H
  __bf16* accRelu = (__bf16*)carve((size_t)N * 512 * 2);
  float*  T1      = (float*)carve((size_t)N * 256 * 4);
  __bf16* Ya      = (__bf16*)carve((size_t)TT * N * 16 * 2);
  __bf16* WyZR    = (__bf16*)carve((size_t)1024 * 16 * 2);
  __bf16* WyH     = (__bf16*)carve((size_t)512 * 16 * 2);
  __bf16* Wy1     = (__bf16*)carve((size_t)256 * 16 * 2);
  int*    cnt     = (int*)carve((size_t)2 * N * 4);  // cnt[N] + fill[N] contiguous
  int*    fill    = cnt + N;
  int*    offs    = (int*)carve((size_t)(N + 1) * 4);
  int*    pscan   = (int*)carve((size_t)N * 4);
  int*    bsum    = (int*)carve(256);
  int*    bpre    = (int*)carve(256);
  int*    csrc    = (int*)carve((size_t)E * 4);
  float*  cw      = (float*)carve((size_t)E * 4);
  const int RB = (N + 63) / 64;  // 157 row blocks
  int*    ctr0    = (int*)carve((size_t)2 * 12 * RB * 4);  // ctr0[12*RB] + ctr1[12*RB]
  int*    ctr1    = ctr0 + 12 * RB;
  (void)carve(512 * 1024);  // tail pad: OOB tile reads stay inside ws
  (void)ws_size; (void)n_in; (void)out_size;

  const int TPB = 256;
  auto cdiv = [](int a, int b) { return (a + b - 1) / b; };
  const size_t S = (size_t)N * 512;

  // degree + CSR counts
  k_init<<<cdiv(N, TPB), TPB, 0, stream>>>(deg, cnt, N);
  k_edge<<<cdiv(E, TPB), TPB, 0, stream>>>(dstI, ea, deg, cnt, E);

  // hierarchical scan (+dinv) -> offs; place; gather Y = Ahat @ X
  const int nb = cdiv(N, 256);
  k_scan1<<<nb, 256, 0, stream>>>(cnt, pscan, bsum, deg, dinv, N);
  k_scan2<<<1, 128, 0, stream>>>(bsum, bpre, nb, att, probs);
  k_scan3<<<cdiv(N, TPB), TPB, 0, stream>>>(pscan, bpre, offs, N, E);
  k_place<<<cdiv(E, TPB), TPB, 0, stream>>>(srcI, dstI, ea, offs, fill, csrc, cw, E);
  k_gather<<<cdiv(N * 12, TPB), TPB, 0, stream>>>(offs, csrc, cw, dinv, x, Y, N);

  // weight prep
  {
    dim3 gp(16, 8, 3);
    k_pack3<<<gp, 256, 0, stream>>>(Wzl, Wrl, Whl, W1, WzrP, WhP, W1P);
  }
  k_build_eff3<<<cdiv(3 * 5 * 512, TPB), TPB, 0, stream>>>(
      Wzg, Wzl, bzg, bzl, Wrg, Wrl, brg, brl, Whg, Whl, bhg, bhl,
      Wzr_eff, bzr_eff, Wh_eff, bh_eff);
  k_wy3<<<cdiv((1024 + 512 + 256) * 16, TPB), TPB, 0, stream>>>(
      Wzr_eff, bzr_eff, Wh_eff, bh_eff, b1, WyZR, WyH, Wy1);

  // merged Ya build + t=0 shortcut (H1 = (1-sigmoid(Yz)) * tanh(Yh))
  k_yat0<<<cdiv(N * 512 + TT * N * 16, TPB), TPB, 0, stream>>>(
      Y, Wzr_eff, bzr_eff, Wh_eff, bh_eff, Ya, hist + S, N);

  // zero dep counters, then the whole GRU t-loop in ONE persistent dispatch
  hipMemsetAsync(ctr0, 0, (size_t)2 * 12 * RB * 4, stream);
  k_tloop<<<768, 256, 0, stream>>>(hist, Zbf, Rbf, WzrP, WhP, WyZR, WyH, Ya,
                                   ctr0, ctr1, N, RB);

  // H_accum = sum_t p_t H_{t+1}; head
  const int RBX = cdiv(RB, 8);
  k_acc<<<cdiv(N * 64, TPB), TPB, 0, stream>>>(hist, probs, accO, accRelu, N);
  k_mm<2><<<8 * RBX * 2, 256, 0, stream>>>(accRelu, W1P, nullptr, nullptr, Ya, Wy1,
                                           T1, nullptr, nullptr, N, RB);
  k_head2<<<cdiv(N * 12, TPB), TPB, 0, stream>>>(T1, W2, b2, out0, N);
}

// Round 5
// 1509.673 us; speedup vs baseline: 1.0661x; 1.0661x over previous
//
#include <hip/hip_runtime.h>
#include <math.h>

// F=4, T=12, C=512, HID=256, OUT=12
#define NF 48
#define TT 12

typedef __bf16 v8bf __attribute__((ext_vector_type(8)));
typedef float v16f __attribute__((ext_vector_type(16)));

// direct global->LDS, 16B per lane; LDS dest must be wave-uniform (HW adds lane*16)
__device__ __forceinline__ void gld16(const void* g, void* l) {
  __builtin_amdgcn_global_load_lds(
      (const __attribute__((address_space(1))) void*)(uintptr_t)g,
      (__attribute__((address_space(3))) void*)(uintptr_t)l, 16, 0, 0);
}

// ---------------- small prep kernels ----------------

__global__ void k_init(float* __restrict__ deg, int* __restrict__ cnt, int n) {
  int i = blockIdx.x * blockDim.x + threadIdx.x;
  if (i < n) { deg[i] = 1.0f; cnt[i] = 0; cnt[n + i] = 0; }
}

__global__ void k_edge(const int* __restrict__ dst, const float* __restrict__ w,
                       float* __restrict__ deg, int* __restrict__ cnt, int e) {
  int i = blockIdx.x * blockDim.x + threadIdx.x;
  if (i < e) {
    int d = dst[i];
    atomicAdd(&deg[d], w[i]);
    atomicAdd(&cnt[d], 1);
  }
}

// ---------------- hierarchical scan (+ dinv fused) ----------------

__global__ void k_scan1(const int* __restrict__ cnt, int* __restrict__ pscan,
                        int* __restrict__ bsum, const float* __restrict__ deg,
                        float* __restrict__ dinv, int n) {
  __shared__ int s[256];
  int i = blockIdx.x * 256 + threadIdx.x;
  int v = (i < n) ? cnt[i] : 0;
  s[threadIdx.x] = v;
  __syncthreads();
  for (int off = 1; off < 256; off <<= 1) {
    int t = 0;
    if (threadIdx.x >= off) t = s[threadIdx.x - off];
    __syncthreads();
    s[threadIdx.x] += t;
    __syncthreads();
  }
  if (i < n) {
    pscan[i] = s[threadIdx.x] - v;
    dinv[i] = rsqrtf(fmaxf(deg[i], 1e-12f));
  }
  if (threadIdx.x == 255) bsum[blockIdx.x] = s[255];
}

__global__ void k_scan2(const int* __restrict__ bsum, int* __restrict__ bpre, int nb,
                        const float* __restrict__ att, float* __restrict__ probs) {
  if (blockIdx.x == 0 && threadIdx.x == 0) {
    int run = 0;
    for (int b = 0; b < nb; b++) { bpre[b] = run; run += bsum[b]; }
  }
  if (blockIdx.x == 0 && threadIdx.x == 64) {
    float m = -1e30f;
    for (int t = 0; t < TT; t++) m = fmaxf(m, att[t]);
    float e[TT], s = 0.f;
    for (int t = 0; t < TT; t++) { e[t] = expf(att[t] - m); s += e[t]; }
    for (int t = 0; t < TT; t++) probs[t] = e[t] / s;
  }
}

__global__ void k_scan3(const int* __restrict__ pscan, const int* __restrict__ bpre,
                        int* __restrict__ offs, int n, int e) {
  int i = blockIdx.x * blockDim.x + threadIdx.x;
  if (i < n) offs[i] = pscan[i] + bpre[i >> 8];
  if (i == 0) offs[n] = e;
}

__global__ void k_place(const int* __restrict__ src, const int* __restrict__ dst,
                        const float* __restrict__ w, const int* __restrict__ offs,
                        int* __restrict__ fill, int* __restrict__ csrc,
                        float* __restrict__ cw, int e) {
  int i = blockIdx.x * blockDim.x + threadIdx.x;
  if (i >= e) return;
  int d = dst[i];
  int p = offs[d] + atomicAdd(&fill[d], 1);
  csrc[p] = src[i];
  cw[p] = w[i];
}

__global__ void k_gather(const int* __restrict__ offs, const int* __restrict__ csrc,
                         const float* __restrict__ cw, const float* __restrict__ dinv,
                         const float* __restrict__ x, float* __restrict__ Y, int n) {
  int tg = blockIdx.x * blockDim.x + threadIdx.x;
  if (tg >= n * 12) return;
  int i = tg / 12, q = tg % 12;
  float di = dinv[i];
  const float4* x4 = (const float4*)x;
  float4 sv = x4[(size_t)i * 12 + q];
  float ax = di * sv.x, ay = di * sv.y, az = di * sv.z, aw = di * sv.w;
  int e1 = offs[i + 1];
  for (int e = offs[i]; e < e1; e++) {
    int s = csrc[e];
    float wv = cw[e] * dinv[s];
    float4 xv = x4[(size_t)s * 12 + q];
    ax = fmaf(wv, xv.x, ax); ay = fmaf(wv, xv.y, ay);
    az = fmaf(wv, xv.z, az); aw = fmaf(wv, xv.w, aw);
  }
  float4 o = make_float4(di * ax, di * ay, di * az, di * aw);
  ((float4*)Y)[(size_t)i * 12 + q] = o;
}

// ---------------- weight prep: LDS-tiled transpose into swizzled pack ----------------
// pack layout: [n/128][k/32][ row=n%128 ][ chunk(16B)^((row>>1)&3) ][ e ]
__device__ __forceinline__ size_t packIdx128(int n, int k) {
  int row = n & 127;
  int c = (k & 31) >> 3;
  return (size_t)(n >> 7) * (128 * 512) + (size_t)(k >> 5) * (128 * 32) +
         (size_t)row * 32 + (size_t)((c ^ ((row >> 1) & 3)) << 3) + (k & 7);
}

__global__ void k_pack3(const float* __restrict__ Wzl, const float* __restrict__ Wrl,
                        const float* __restrict__ Whl, const float* __restrict__ W1,
                        __bf16* __restrict__ WzrP, __bf16* __restrict__ WhP,
                        __bf16* __restrict__ W1P) {
  __shared__ __bf16 t[64][72];
  int modew = blockIdx.z;
  if (modew == 1 && blockIdx.x >= 8) return;
  if (modew == 2 && blockIdx.x >= 4) return;
  int n0 = blockIdx.x * 64, k0 = blockIdx.y * 64;
  __bf16* WT = (modew == 0) ? WzrP : (modew == 1) ? WhP : W1P;
#pragma unroll
  for (int p = 0; p < 4; p++) {
    int kk = p * 16 + (threadIdx.x >> 4);
    int nn = (threadIdx.x & 15) * 4;
    int n = n0 + nn, k = k0 + kk;
    float4 v;
    if (modew == 2) {
      v = *(const float4*)(W1 + (size_t)k * 256 + n);
    } else {
      const float* src = (modew == 1) ? Whl : Wzl;
      int nc = n;
      if (modew == 0 && n >= 512) { src = Wrl; nc = n - 512; }
      v = *(const float4*)(src + (size_t)(512 + k) * 512 + nc);
    }
    t[kk][nn + 0] = (__bf16)v.x; t[kk][nn + 1] = (__bf16)v.y;
    t[kk][nn + 2] = (__bf16)v.z; t[kk][nn + 3] = (__bf16)v.w;
  }
  __syncthreads();
#pragma unroll
  for (int u = 0; u < 2; u++) {
    int unit = threadIdx.x * 2 + u;
    int nl = unit >> 3, kg = unit & 7;
    v8bf o;
#pragma unroll
    for (int j = 0; j < 8; j++) o[j] = t[kg * 8 + j][nl];
    *(v8bf*)(WT + packIdx128(n0 + nl, k0 + kg * 8)) = o;
  }
}

__global__ void k_build_eff3(const float* __restrict__ Wzg, const float* __restrict__ Wzl,
                             const float* __restrict__ bzg, const float* __restrict__ bzl,
                             const float* __restrict__ Wrg, const float* __restrict__ Wrl,
                             const float* __restrict__ brg, const float* __restrict__ brl,
                             const float* __restrict__ Whg, const float* __restrict__ Whl,
                             const float* __restrict__ bhg, const float* __restrict__ bhl,
                             float* __restrict__ WzrE, float* __restrict__ bzrE,
                             float* __restrict__ WhE, float* __restrict__ bhE) {
  int idx = blockIdx.x * blockDim.x + threadIdx.x;
  if (idx >= 3 * 5 * 512) return;
  int seg = idx / 2560;
  int r = (idx % 2560) / 512, c = idx % 512;
  const float *Wg, *Wl, *bg, *bl;
  float *We, *be;
  int ostride, ooff;
  if (seg == 0) { Wg = Wzg; Wl = Wzl; bg = bzg; bl = bzl; We = WzrE; be = bzrE; ostride = 1024; ooff = 0; }
  else if (seg == 1) { Wg = Wrg; Wl = Wrl; bg = brg; bl = brl; We = WzrE; be = bzrE; ostride = 1024; ooff = 512; }
  else { Wg = Whg; Wl = Whl; bg = bhg; bl = bhl; We = WhE; be = bhE; ostride = 512; ooff = 0; }
  float s = 0.f;
  if (r < 4) {
    for (int k = 0; k < 512; k++) s += Wg[r * 512 + k] * Wl[k * 512 + c];
    We[r * ostride + ooff + c] = s;
  } else {
    for (int k = 0; k < 512; k++) s += bg[k] * Wl[k * 512 + c];
    be[ooff + c] = s + bl[c];
  }
}

__global__ void k_wy3(const float* __restrict__ WzrE, const float* __restrict__ bzrE,
                      const float* __restrict__ WhE, const float* __restrict__ bhE,
                      const float* __restrict__ b1,
                      __bf16* __restrict__ WyZR, __bf16* __restrict__ WyH,
                      __bf16* __restrict__ Wy1) {
  int idx = blockIdx.x * blockDim.x + threadIdx.x;
  const float* Weff; const float* beff; __bf16* out; int Nout, loc;
  if (idx < 1024 * 16) { Weff = WzrE; beff = bzrE; out = WyZR; Nout = 1024; loc = idx; }
  else if (idx < (1024 + 512) * 16) { Weff = WhE; beff = bhE; out = WyH; Nout = 512; loc = idx - 1024 * 16; }
  else if (idx < (1024 + 512 + 256) * 16) { Weff = nullptr; beff = b1; out = Wy1; Nout = 256; loc = idx - (1024 + 512) * 16; }
  else return;
  int n = loc >> 4, k = loc & 15;
  float v = 0.f;
  if (k < 4) v = Weff ? Weff[k * Nout + n] : 0.f;
  else if (k == 4) v = beff[n];
  out[(size_t)(n >> 7) * 2048 + (size_t)(n & 127) * 16 + k] = (__bf16)v;
}

__global__ void k_yat0(const float* __restrict__ Y,
                       const float* __restrict__ WzrE, const float* __restrict__ bzrE,
                       const float* __restrict__ WhE, const float* __restrict__ bhE,
                       __bf16* __restrict__ Ya, __bf16* __restrict__ H1, int n) {
  int idx = blockIdx.x * blockDim.x + threadIdx.x;
  int nt0 = n * 512;
  if (idx < nt0) {
    int i = idx >> 9, c = idx & 511;
    float y0 = Y[(size_t)i * NF + 0], y1 = Y[(size_t)i * NF + 12];
    float y2 = Y[(size_t)i * NF + 24], y3 = Y[(size_t)i * NF + 36];
    float pz = bzrE[c] + y0 * WzrE[c] + y1 * WzrE[1024 + c] +
               y2 * WzrE[2048 + c] + y3 * WzrE[3072 + c];
    float ph = bhE[c] + y0 * WhE[c] + y1 * WhE[512 + c] +
               y2 * WhE[1024 + c] + y3 * WhE[1536 + c];
    float z = 1.f / (1.f + expf(-pz));
    H1[idx] = (__bf16)((1.f - z) * tanhf(ph));
  } else {
    int r = idx - nt0;
    if (r >= TT * n * 16) return;
    int t = r / (n * 16);
    int loc = r % (n * 16);
    int nn = loc >> 4, k = loc & 15;
    float v = 0.f;
    if (k < 4) v = Y[(size_t)nn * NF + k * TT + t];
    else if (k == 4) v = 1.f;
    Ya[r] = (__bf16)v;
  }
}

// ---------------- persistent row-resident GRU: one block owns 64 rows for all t ----------------
// H lives in LDS (swizzled) for the whole recurrence. Weights streamed per strip via
// counted-vmcnt 3-buffer pipeline. ZERO cross-block communication (R4 lesson: agent
// fences destroy L2). 8 waves = 2 row-halves x 4 col-quads; wave tile 32x64.
__global__ __launch_bounds__(512, 1) void k_gru(
    const __bf16* __restrict__ H1, __bf16* __restrict__ hist,
    const __bf16* __restrict__ WzrP, const __bf16* __restrict__ WhP,
    const __bf16* __restrict__ WyZR, const __bf16* __restrict__ WyH,
    const __bf16* __restrict__ Ya, int M) {
  // LDS map (bf16 elems): H 0..32767 | B dbuf 3x8192 @32768 | Wy 4096 @57344 | Ay 1024 @61440
  __shared__ __bf16 smem[62464];
  constexpr int BOFF = 32768, WYOFF = 57344, AYOFF = 61440;
  const int row0 = blockIdx.x * 64;
  const int tid = threadIdx.x;
  const int lane = tid & 63, w = tid >> 6;
  const int h = w >> 2, q = w & 3;
  const int l31 = lane & 31, lh = lane >> 5;
  const size_t S = (size_t)M * 512;

  // gemm over one 256-col strip: acc[2] tiles (cols q*64 + ni*32), K=512 + 16 Y-term
  auto gemmStrip = [&](const __bf16* Bpack, int p0, const __bf16* Wysrc, v16f* acc) {
    gld16(Wysrc + (size_t)p0 * 2048 + (size_t)tid * 8, smem + WYOFF + w * 512);
    auto stageB = [&](int buf, int kc) {
      const __bf16* src = Bpack + (size_t)p0 * 65536 + (size_t)kc * 4096 + (size_t)tid * 8;
      gld16(src, smem + BOFF + buf * 8192 + w * 512);
      gld16(src + 65536, smem + BOFF + buf * 8192 + 4096 + w * 512);
    };
    stageB(0, 0);
    stageB(1, 1);
#pragma unroll
    for (int kc = 0; kc < 16; kc++) {
      if (kc < 15)
        asm volatile("s_waitcnt vmcnt(2) lgkmcnt(0)\n\ts_barrier" ::: "memory");
      else
        asm volatile("s_waitcnt vmcnt(0) lgkmcnt(0)\n\ts_barrier" ::: "memory");
      if (kc < 14) stageB((kc + 2) % 3, kc + 2);
      const __bf16* B = smem + BOFF + (kc % 3) * 8192;
      __builtin_amdgcn_s_setprio(1);
#pragma unroll
      for (int k16 = 0; k16 < 2; k16++) {
        int row = h * 32 + l31;
        int k8 = k16 * 2 + lh;
        v8bf a = *(const v8bf*)&smem[row * 512 + kc * 32 +
                                     ((k8 ^ ((row >> 1) & 3)) << 3)];
#pragma unroll
        for (int ni = 0; ni < 2; ni++) {
          int n = q * 64 + ni * 32 + l31;
          v8bf b = *(const v8bf*)&B[n * 32 + ((k8 ^ ((n >> 1) & 3)) << 3)];
          acc[ni] = __builtin_amdgcn_mfma_f32_32x32x16_bf16(a, b, acc[ni], 0, 0, 0);
        }
      }
      __builtin_amdgcn_s_setprio(0);
    }
    // Y-term (K extension by 16: A=Ay rows, B=Wy strip)
    {
      v8bf a = *(const v8bf*)&smem[AYOFF + (h * 32 + l31) * 16 + lh * 8];
#pragma unroll
      for (int ni = 0; ni < 2; ni++) {
        v8bf b = *(const v8bf*)&smem[WYOFF + (q * 64 + ni * 32 + l31) * 16 + lh * 8];
        acc[ni] = __builtin_amdgcn_mfma_f32_32x32x16_bf16(a, b, acc[ni], 0, 0, 0);
      }
    }
    __syncthreads();  // strip end: B0/Wy regions reused by next strip
  };

  // ---- preload H_1 into LDS (linear dest, source pre-XORed so content is swizzled) ----
#pragma unroll
  for (int j = 0; j < 8; j++) {
    int grp = tid + j * 512;
    int row = grp >> 6, gp = grp & 63;
    int gl = (gp & ~3) | ((gp & 3) ^ ((row >> 1) & 3));
    gld16(H1 + (size_t)(row0 + row) * 512 + (size_t)gl * 8,
          smem + ((size_t)j * 512 + (size_t)w * 64) * 8);
  }
  asm volatile("s_waitcnt vmcnt(0)" ::: "memory");
  __syncthreads();

  v8bf zpk[2][2][2], rpk[2][2][2], hpk[2][2][2];

  for (int t = 1; t < TT; t++) {
    if (tid < 128)
      gld16(Ya + ((size_t)t * M + row0) * 16 + (size_t)tid * 8, smem + AYOFF + w * 512);

    // ---- zr phase: 4 strips over 1024 cols; z -> zpk, r -> rpk (C-layout bf16 regs) ----
#pragma unroll
    for (int s = 0; s < 4; s++) {
      v16f acc[2];
#pragma unroll
      for (int ni = 0; ni < 2; ni++)
#pragma unroll
        for (int r2 = 0; r2 < 16; r2++) acc[ni][r2] = 0.f;
      gemmStrip(WzrP, 2 * s, WyZR, acc);
#pragma unroll
      for (int ni = 0; ni < 2; ni++)
#pragma unroll
        for (int reg = 0; reg < 16; reg++) {
          float v = 1.f / (1.f + expf(-acc[ni][reg]));
          if (s < 2) zpk[s][ni][reg >> 3][reg & 7] = (__bf16)v;
          else rpk[s - 2][ni][reg >> 3][reg & 7] = (__bf16)v;
        }
    }

    // ---- H <- r*H in place (each lane owns disjoint C-layout elems); stash H ----
#pragma unroll
    for (int sp = 0; sp < 2; sp++)
#pragma unroll
      for (int ni = 0; ni < 2; ni++) {
        int col = sp * 256 + q * 64 + ni * 32 + l31;
        int cb = (col >> 5) << 5, c3 = (col >> 3) & 3, c7 = col & 7;
#pragma unroll
        for (int reg = 0; reg < 16; reg++) {
          int row = h * 32 + (reg & 3) + ((reg >> 2) << 3) + (lh << 2);
          int ad = row * 512 + cb + ((c3 ^ ((row >> 1) & 3)) << 3) + c7;
          float hv = (float)smem[ad];
          hpk[sp][ni][reg >> 3][reg & 7] = (__bf16)hv;
          smem[ad] = (__bf16)((float)rpk[sp][ni][reg >> 3][reg & 7] * hv);
        }
      }
    __syncthreads();

    // ---- h phase: 2 strips over 512 cols, A = r*H (in LDS) ----
    v16f acch[2][2];
#pragma unroll
    for (int sp = 0; sp < 2; sp++)
#pragma unroll
      for (int ni = 0; ni < 2; ni++)
#pragma unroll
        for (int r2 = 0; r2 < 16; r2++) acch[sp][ni][r2] = 0.f;
#pragma unroll
    for (int s = 0; s < 2; s++) gemmStrip(WhP, 2 * s, WyH, acch[s]);

    // ---- blend: H_{t+1} = z*H + (1-z)*tanh(ht); write into LDS H ----
#pragma unroll
    for (int sp = 0; sp < 2; sp++)
#pragma unroll
      for (int ni = 0; ni < 2; ni++) {
        int col = sp * 256 + q * 64 + ni * 32 + l31;
        int cb = (col >> 5) << 5, c3 = (col >> 3) & 3, c7 = col & 7;
#pragma unroll
        for (int reg = 0; reg < 16; reg++) {
          int row = h * 32 + (reg & 3) + ((reg >> 2) << 3) + (lh << 2);
          float ht = tanhf(acch[sp][ni][reg]);
          float z = (float)zpk[sp][ni][reg >> 3][reg & 7];
          float hs = (float)hpk[sp][ni][reg >> 3][reg & 7];
          int ad = row * 512 + cb + ((c3 ^ ((row >> 1) & 3)) << 3) + c7;
          smem[ad] = (__bf16)(z * hs + (1.f - z) * ht);
        }
      }
    __syncthreads();

    // ---- stream H_{t+1} to hist (coalesced; LDS read applies inverse swizzle) ----
    __bf16* Hn = hist + (size_t)(t + 1) * S;
#pragma unroll
    for (int j = 0; j < 8; j++) {
      int grp = tid + j * 512;
      int row = grp >> 6, gp = grp & 63;
      int rg = row0 + row;
      int ad = row * 512 + (gp & ~3) * 8 + (((gp & 3) ^ ((row >> 1) & 3)) << 3);
      uint4 vv = *(const uint4*)&smem[ad];
      if (rg < M) *(uint4*)(Hn + (size_t)rg * 512 + (size_t)gp * 8) = vv;
    }
    // no barrier needed: next t touches only Ay/B regions before its strip barriers
  }
}

// ---------------- MODE2 head GEMM (R15 structure, 64x128 tile) ----------------
template <int MODE>
__global__ __launch_bounds__(256, 4) void k_mm(
    const __bf16* __restrict__ Agm, const __bf16* __restrict__ Bp,
    const __bf16* __restrict__ Ay, const __bf16* __restrict__ Wy,
    float* __restrict__ Ofp, int M, int RB) {
  constexpr int BUFS = 6144;
  __shared__ __bf16 smem[21504];

  const int RBX = (RB + 7) >> 3;
  int xcd = blockIdx.x & 7;
  int idx = blockIdx.x >> 3;
  int rowblk = xcd * RBX + idx % RBX;
  int colblk = idx / RBX;
  if (rowblk >= RB) return;

  const int row0 = rowblk * 64;
  const int tid = threadIdx.x;
  const int lane = tid & 63, w = tid >> 6;
  const int wr = (w >> 1) * 32, wc = (w & 1) * 64;
  const int l31 = lane & 31, lh = lane >> 5;

  const int ar = tid >> 2, ac = tid & 3;
  const __bf16* At = Agm + (size_t)(row0 + ar) * 512 + ((ac ^ ((ar >> 1) & 3)) << 3);
  const __bf16* Bt = Bp + (size_t)colblk * (128 * 512);

  v16f acc[2];
#pragma unroll
  for (int j = 0; j < 2; j++)
#pragma unroll
    for (int p = 0; p < 16; p++) acc[j][p] = 0.f;

  auto stage = [&](int buf, int kt) {
    __bf16* base = smem + buf * BUFS;
    gld16(At + kt * 32, base + w * 512);
    const __bf16* bs = Bt + (size_t)kt * 4096 + (size_t)tid * 8;
    gld16(bs, base + 2048 + w * 512);
    gld16(bs + 2048, base + 4096 + w * 512);
  };
  auto stageY = [&]() {
    if (w < 2)
      gld16(Ay + (size_t)(row0 + (tid >> 1)) * 16 + (tid & 1) * 8,
            smem + 18432 + w * 512);
    gld16(Wy + (size_t)colblk * 2048 + (size_t)tid * 8, smem + 19456 + w * 512);
  };
  auto compute = [&](int buf) {
    const __bf16* base = smem + buf * BUFS;
    __builtin_amdgcn_s_setprio(1);
#pragma unroll
    for (int ks = 0; ks < 2; ks++) {
      int kc = ks * 2 + lh;
      int fr = wr + l31;
      v8bf a = *(const v8bf*)&base[fr * 32 + ((kc ^ ((fr >> 1) & 3)) << 3)];
#pragma unroll
      for (int ni = 0; ni < 2; ni++) {
        int fc = wc + ni * 32 + l31;
        v8bf b = *(const v8bf*)&base[2048 + fc * 32 + ((kc ^ ((fc >> 1) & 3)) << 3)];
        acc[ni] = __builtin_amdgcn_mfma_f32_32x32x16_bf16(a, b, acc[ni], 0, 0, 0);
      }
    }
    __builtin_amdgcn_s_setprio(0);
  };

  stageY();
  stage(0, 0);
  stage(1, 1);
#pragma unroll
  for (int kt = 0; kt < 16; kt++) {
    if (kt < 15)
      asm volatile("s_waitcnt vmcnt(3) lgkmcnt(0)\n\ts_barrier" ::: "memory");
    else
      asm volatile("s_waitcnt vmcnt(0) lgkmcnt(0)\n\ts_barrier" ::: "memory");
    if (kt < 14) stage((kt + 2) % 3, kt + 2);
    compute(kt % 3);
  }
  {
    const __bf16* ya = smem + 18432;
    const __bf16* yb = smem + 19456;
    v8bf a = *(const v8bf*)&ya[(wr + l31) * 16 + lh * 8];
#pragma unroll
    for (int ni = 0; ni < 2; ni++) {
      v8bf b = *(const v8bf*)&yb[(wc + ni * 32 + l31) * 16 + lh * 8];
      acc[ni] = __builtin_amdgcn_mfma_f32_32x32x16_bf16(a, b, acc[ni], 0, 0, 0);
    }
  }
  __syncthreads();

  if constexpr (MODE == 2) {
#pragma unroll
    for (int ni = 0; ni < 2; ni++) {
      int cl = wc + ni * 32 + l31;
#pragma unroll
      for (int reg = 0; reg < 16; reg++) {
        int rg = row0 + wr + (reg & 3) + ((reg >> 2) << 3) + (lh << 2);
        if (rg >= M) continue;
        Ofp[(size_t)rg * 256 + colblk * 128 + cl] = fmaxf(acc[ni][reg], 0.f);
      }
    }
  }
}

// acc[i,c] = sum_t probs[t] * hist[t+1][i,c];  accRelu = bf16(relu(acc))
__global__ void k_acc(const __bf16* __restrict__ hist, const float* __restrict__ probs,
                      float* __restrict__ acc, __bf16* __restrict__ accRelu, int n) {
  int idx = blockIdx.x * blockDim.x + threadIdx.x;
  if (idx >= n * 64) return;
  size_t off = (size_t)idx * 8;
  size_t S = (size_t)n * 512;
  float s[8] = {0, 0, 0, 0, 0, 0, 0, 0};
#pragma unroll
  for (int t = 0; t < TT; t++) {
    float p = probs[t];
    v8bf h = *(const v8bf*)(hist + (size_t)(t + 1) * S + off);
#pragma unroll
    for (int j = 0; j < 8; j++) s[j] = fmaf(p, (float)h[j], s[j]);
  }
  *(float4*)(acc + off) = make_float4(s[0], s[1], s[2], s[3]);
  *(float4*)(acc + off + 4) = make_float4(s[4], s[5], s[6], s[7]);
  v8bf rl;
#pragma unroll
  for (int j = 0; j < 8; j++) rl[j] = (__bf16)fmaxf(s[j], 0.f);
  *(v8bf*)(accRelu + off) = rl;
}

__global__ void k_head2(const float* __restrict__ T1, const float* __restrict__ W2,
                        const float* __restrict__ b2, float* __restrict__ out0, int M) {
  int idx = blockIdx.x * blockDim.x + threadIdx.x;
  if (idx >= M * 12) return;
  int i = idx / 12, c = idx % 12;
  const float* tr = T1 + (size_t)i * 256;
  float s = b2[c];
  for (int k = 0; k < 256; k++) s = fmaf(tr[k], W2[k * 12 + c], s);
  out0[idx] = s;
}

// ---------------- launch ----------------

extern "C" void kernel_launch(void* const* d_in, const int* in_sizes, int n_in,
                              void* d_out, int out_size, void* d_ws, size_t ws_size,
                              hipStream_t stream) {
  const float* x   = (const float*)d_in[0];
  const int*   ei  = (const int*)d_in[1];
  const float* ea  = (const float*)d_in[2];
  const float* att = (const float*)d_in[3];
  const float* Wzg = (const float*)d_in[4];  const float* bzg = (const float*)d_in[5];
  const float* Wzl = (const float*)d_in[6];  const float* bzl = (const float*)d_in[7];
  const float* Wrg = (const float*)d_in[8];  const float* brg = (const float*)d_in[9];
  const float* Wrl = (const float*)d_in[10]; const float* brl = (const float*)d_in[11];
  const float* Whg = (const float*)d_in[12]; const float* bhg = (const float*)d_in[13];
  const float* Whl = (const float*)d_in[14]; const float* bhl = (const float*)d_in[15];
  const float* W1  = (const float*)d_in[16]; const float* b1  = (const float*)d_in[17];
  const float* W2  = (const float*)d_in[18]; const float* b2  = (const float*)d_in[19];

  const int N = in_sizes[0] / NF;
  const int E = in_sizes[1] / 2;
  const int* srcI = ei;
  const int* dstI = ei + E;

  float* out0 = (float*)d_out;                   // [N,12]
  float* accO = (float*)d_out + (size_t)N * 12;  // [N,512] = H_accum (output 1)

  char* wp = (char*)d_ws;
  auto carve = [&](size_t bytes) -> void* {
    void* p = (void*)wp;
    wp += (bytes + 255) & ~(size_t)255;
    return p;
  };
  float*  deg     = (float*)carve((size_t)N * 4);
  float*  dinv    = (float*)carve((size_t)N * 4);
  float*  probs   = (float*)carve(64);
  float*  Y       = (float*)carve((size_t)N * NF * 4);
  __bf16* WzrP    = (__bf16*)carve((size_t)1024 * 512 * 2);
  __bf16* WhP     = (__bf16*)carve((size_t)512 * 512 * 2);
  __bf16* W1P     = (__bf16*)carve((size_t)256 * 512 * 2);
  float*  Wzr_eff = (float*)carve((size_t)4 * 1024 * 4);
  float*  bzr_eff = (float*)carve((size_t)1024 * 4);
  float*  Wh_eff  = (float*)carve((size_t)4 * 512 * 4);
  float*  bh_eff  = (float*)carve((size_t)512 * 4);
  __bf16* hist    = (__bf16*)carve((size_t)(TT + 1) * N * 512 * 2);  // H_0..H_12 bf16
  __bf16* accRelu = (__bf16*)carve((size_t)N * 512 * 2);
  float*  T1      = (float*)carve((size_t)N * 256 * 4);
  __bf16* Ya      = (__bf16*)carve((size_t)TT * N * 16 * 2);
  __bf16* WyZR    = (__bf16*)carve((size_t)1024 * 16 * 2);
  __bf16* WyH     = (__bf16*)carve((size_t)512 * 16 * 2);
  __bf16* Wy1     = (__bf16*)carve((size_t)256 * 16 * 2);
  int*    cnt     = (int*)carve((size_t)2 * N * 4);  // cnt[N] + fill[N] contiguous
  int*    fill    = cnt + N;
  int*    offs    = (int*)carve((size_t)(N + 1) * 4);
  int*    pscan   = (int*)carve((size_t)N * 4);
  int*    bsum    = (int*)carve(256);
  int*    bpre    = (int*)carve(256);
  int*    csrc    = (int*)carve((size_t)E * 4);
  float*  cw      = (float*)carve((size_t)E * 4);
  (void)carve(512 * 1024);  // tail pad: OOB tile reads stay inside ws
  (void)ws_size; (void)n_in; (void)out_size;

  const int TPB = 256;
  auto cdiv = [](int a, int b) { return (a + b - 1) / b; };
  const size_t S = (size_t)N * 512;

  // degree + CSR counts
  k_init<<<cdiv(N, TPB), TPB, 0, stream>>>(deg, cnt, N);
  k_edge<<<cdiv(E, TPB), TPB, 0, stream>>>(dstI, ea, deg, cnt, E);

  // hierarchical scan (+dinv) -> offs; place; gather Y = Ahat @ X
  const int nb = cdiv(N, 256);
  k_scan1<<<nb, 256, 0, stream>>>(cnt, pscan, bsum, deg, dinv, N);
  k_scan2<<<1, 128, 0, stream>>>(bsum, bpre, nb, att, probs);
  k_scan3<<<cdiv(N, TPB), TPB, 0, stream>>>(pscan, bpre, offs, N, E);
  k_place<<<cdiv(E, TPB), TPB, 0, stream>>>(srcI, dstI, ea, offs, fill, csrc, cw, E);
  k_gather<<<cdiv(N * 12, TPB), TPB, 0, stream>>>(offs, csrc, cw, dinv, x, Y, N);

  // weight prep
  {
    dim3 gp(16, 8, 3);
    k_pack3<<<gp, 256, 0, stream>>>(Wzl, Wrl, Whl, W1, WzrP, WhP, W1P);
  }
  k_build_eff3<<<cdiv(3 * 5 * 512, TPB), TPB, 0, stream>>>(
      Wzg, Wzl, bzg, bzl, Wrg, Wrl, brg, brl, Whg, Whl, bhg, bhl,
      Wzr_eff, bzr_eff, Wh_eff, bh_eff);
  k_wy3<<<cdiv((1024 + 512 + 256) * 16, TPB), TPB, 0, stream>>>(
      Wzr_eff, bzr_eff, Wh_eff, bh_eff, b1, WyZR, WyH, Wy1);

  // merged Ya build + t=0 shortcut (H1 = (1-sigmoid(Yz)) * tanh(Yh))
  k_yat0<<<cdiv(N * 512 + TT * N * 16, TPB), TPB, 0, stream>>>(
      Y, Wzr_eff, bzr_eff, Wh_eff, bh_eff, Ya, hist + S, N);

  // entire GRU recurrence: one dispatch, row-resident blocks, no cross-block sync
  const int RB = cdiv(N, 64);  // 157
  k_gru<<<RB, 512, 0, stream>>>(hist + S, hist, WzrP, WhP, WyZR, WyH, Ya, N);

  // H_accum = sum_t p_t H_{t+1}; head
  const int RBX = cdiv(RB, 8);
  k_acc<<<cdiv(N * 64, TPB), TPB, 0, stream>>>(hist, probs, accO, accRelu, N);
  k_mm<2><<<8 * RBX * 2, 256, 0, stream>>>(accRelu, W1P, Ya, Wy1, T1, N, RB);
  k_head2<<<cdiv(N * 12, TPB), TPB, 0, stream>>>(T1, W2, b2, out0, N);
}

// Round 6
// 765.693 us; speedup vs baseline: 2.1021x; 1.9716x over previous
//
#include <hip/hip_runtime.h>
#include <math.h>

// F=4, T=12, C=512, HID=256, OUT=12
#define NF 48
#define TT 12

typedef __bf16 v8bf __attribute__((ext_vector_type(8)));
typedef float v16f __attribute__((ext_vector_type(16)));

// direct global->LDS, 16B per lane; LDS dest must be wave-uniform (HW adds lane*16)
__device__ __forceinline__ void gld16(const void* g, void* l) {
  __builtin_amdgcn_global_load_lds(
      (const __attribute__((address_space(1))) void*)(uintptr_t)g,
      (__attribute__((address_space(3))) void*)(uintptr_t)l, 16, 0, 0);
}

// ---------------- small prep kernels ----------------

__global__ void k_init(float* __restrict__ deg, int* __restrict__ cnt, int n) {
  int i = blockIdx.x * blockDim.x + threadIdx.x;
  if (i < n) { deg[i] = 1.0f; cnt[i] = 0; cnt[n + i] = 0; }
}

__global__ void k_edge(const int* __restrict__ dst, const float* __restrict__ w,
                       float* __restrict__ deg, int* __restrict__ cnt, int e) {
  int i = blockIdx.x * blockDim.x + threadIdx.x;
  if (i < e) {
    int d = dst[i];
    atomicAdd(&deg[d], w[i]);
    atomicAdd(&cnt[d], 1);
  }
}

// ---------------- hierarchical scan (+ dinv fused) ----------------

__global__ void k_scan1(const int* __restrict__ cnt, int* __restrict__ pscan,
                        int* __restrict__ bsum, const float* __restrict__ deg,
                        float* __restrict__ dinv, int n) {
  __shared__ int s[256];
  int i = blockIdx.x * 256 + threadIdx.x;
  int v = (i < n) ? cnt[i] : 0;
  s[threadIdx.x] = v;
  __syncthreads();
  for (int off = 1; off < 256; off <<= 1) {
    int t = 0;
    if (threadIdx.x >= off) t = s[threadIdx.x - off];
    __syncthreads();
    s[threadIdx.x] += t;
    __syncthreads();
  }
  if (i < n) {
    pscan[i] = s[threadIdx.x] - v;
    dinv[i] = rsqrtf(fmaxf(deg[i], 1e-12f));
  }
  if (threadIdx.x == 255) bsum[blockIdx.x] = s[255];
}

__global__ void k_scan2(const int* __restrict__ bsum, int* __restrict__ bpre, int nb,
                        const float* __restrict__ att, float* __restrict__ probs) {
  if (blockIdx.x == 0 && threadIdx.x == 0) {
    int run = 0;
    for (int b = 0; b < nb; b++) { bpre[b] = run; run += bsum[b]; }
  }
  if (blockIdx.x == 0 && threadIdx.x == 64) {
    float m = -1e30f;
    for (int t = 0; t < TT; t++) m = fmaxf(m, att[t]);
    float e[TT], s = 0.f;
    for (int t = 0; t < TT; t++) { e[t] = expf(att[t] - m); s += e[t]; }
    for (int t = 0; t < TT; t++) probs[t] = e[t] / s;
  }
}

__global__ void k_scan3(const int* __restrict__ pscan, const int* __restrict__ bpre,
                        int* __restrict__ offs, int n, int e) {
  int i = blockIdx.x * blockDim.x + threadIdx.x;
  if (i < n) offs[i] = pscan[i] + bpre[i >> 8];
  if (i == 0) offs[n] = e;
}

__global__ void k_place(const int* __restrict__ src, const int* __restrict__ dst,
                        const float* __restrict__ w, const int* __restrict__ offs,
                        int* __restrict__ fill, int* __restrict__ csrc,
                        float* __restrict__ cw, int e) {
  int i = blockIdx.x * blockDim.x + threadIdx.x;
  if (i >= e) return;
  int d = dst[i];
  int p = offs[d] + atomicAdd(&fill[d], 1);
  csrc[p] = src[i];
  cw[p] = w[i];
}

__global__ void k_gather(const int* __restrict__ offs, const int* __restrict__ csrc,
                         const float* __restrict__ cw, const float* __restrict__ dinv,
                         const float* __restrict__ x, float* __restrict__ Y, int n) {
  int tg = blockIdx.x * blockDim.x + threadIdx.x;
  if (tg >= n * 12) return;
  int i = tg / 12, q = tg % 12;
  float di = dinv[i];
  const float4* x4 = (const float4*)x;
  float4 sv = x4[(size_t)i * 12 + q];
  float ax = di * sv.x, ay = di * sv.y, az = di * sv.z, aw = di * sv.w;
  int e1 = offs[i + 1];
  for (int e = offs[i]; e < e1; e++) {
    int s = csrc[e];
    float wv = cw[e] * dinv[s];
    float4 xv = x4[(size_t)s * 12 + q];
    ax = fmaf(wv, xv.x, ax); ay = fmaf(wv, xv.y, ay);
    az = fmaf(wv, xv.z, az); aw = fmaf(wv, xv.w, aw);
  }
  float4 o = make_float4(di * ax, di * ay, di * az, di * aw);
  ((float4*)Y)[(size_t)i * 12 + q] = o;
}

// ---------------- weight prep: LDS-tiled transpose into swizzled pack ----------------
// pack layout: [n/128][k/32][ row=n%128 ][ chunk(16B)^((row>>1)&3) ][ e ]
__device__ __forceinline__ size_t packIdx128(int n, int k) {
  int row = n & 127;
  int c = (k & 31) >> 3;
  return (size_t)(n >> 7) * (128 * 512) + (size_t)(k >> 5) * (128 * 32) +
         (size_t)row * 32 + (size_t)((c ^ ((row >> 1) & 3)) << 3) + (k & 7);
}

__global__ void k_pack3(const float* __restrict__ Wzl, const float* __restrict__ Wrl,
                        const float* __restrict__ Whl, const float* __restrict__ W1,
                        __bf16* __restrict__ WzrP, __bf16* __restrict__ WhP,
                        __bf16* __restrict__ W1P) {
  __shared__ __bf16 t[64][72];
  int modew = blockIdx.z;
  if (modew == 1 && blockIdx.x >= 8) return;
  if (modew == 2 && blockIdx.x >= 4) return;
  int n0 = blockIdx.x * 64, k0 = blockIdx.y * 64;
  __bf16* WT = (modew == 0) ? WzrP : (modew == 1) ? WhP : W1P;
#pragma unroll
  for (int p = 0; p < 4; p++) {
    int kk = p * 16 + (threadIdx.x >> 4);
    int nn = (threadIdx.x & 15) * 4;
    int n = n0 + nn, k = k0 + kk;
    float4 v;
    if (modew == 2) {
      v = *(const float4*)(W1 + (size_t)k * 256 + n);
    } else {
      const float* src = (modew == 1) ? Whl : Wzl;
      int nc = n;
      if (modew == 0 && n >= 512) { src = Wrl; nc = n - 512; }
      v = *(const float4*)(src + (size_t)(512 + k) * 512 + nc);
    }
    t[kk][nn + 0] = (__bf16)v.x; t[kk][nn + 1] = (__bf16)v.y;
    t[kk][nn + 2] = (__bf16)v.z; t[kk][nn + 3] = (__bf16)v.w;
  }
  __syncthreads();
#pragma unroll
  for (int u = 0; u < 2; u++) {
    int unit = threadIdx.x * 2 + u;
    int nl = unit >> 3, kg = unit & 7;
    v8bf o;
#pragma unroll
    for (int j = 0; j < 8; j++) o[j] = t[kg * 8 + j][nl];
    *(v8bf*)(WT + packIdx128(n0 + nl, k0 + kg * 8)) = o;
  }
}

__global__ void k_build_eff3(const float* __restrict__ Wzg, const float* __restrict__ Wzl,
                             const float* __restrict__ bzg, const float* __restrict__ bzl,
                             const float* __restrict__ Wrg, const float* __restrict__ Wrl,
                             const float* __restrict__ brg, const float* __restrict__ brl,
                             const float* __restrict__ Whg, const float* __restrict__ Whl,
                             const float* __restrict__ bhg, const float* __restrict__ bhl,
                             float* __restrict__ WzrE, float* __restrict__ bzrE,
                             float* __restrict__ WhE, float* __restrict__ bhE) {
  int idx = blockIdx.x * blockDim.x + threadIdx.x;
  if (idx >= 3 * 5 * 512) return;
  int seg = idx / 2560;
  int r = (idx % 2560) / 512, c = idx % 512;
  const float *Wg, *Wl, *bg, *bl;
  float *We, *be;
  int ostride, ooff;
  if (seg == 0) { Wg = Wzg; Wl = Wzl; bg = bzg; bl = bzl; We = WzrE; be = bzrE; ostride = 1024; ooff = 0; }
  else if (seg == 1) { Wg = Wrg; Wl = Wrl; bg = brg; bl = brl; We = WzrE; be = bzrE; ostride = 1024; ooff = 512; }
  else { Wg = Whg; Wl = Whl; bg = bhg; bl = bhl; We = WhE; be = bhE; ostride = 512; ooff = 0; }
  float s = 0.f;
  if (r < 4) {
    for (int k = 0; k < 512; k++) s += Wg[r * 512 + k] * Wl[k * 512 + c];
    We[r * ostride + ooff + c] = s;
  } else {
    for (int k = 0; k < 512; k++) s += bg[k] * Wl[k * 512 + c];
    be[ooff + c] = s + bl[c];
  }
}

__global__ void k_wy3(const float* __restrict__ WzrE, const float* __restrict__ bzrE,
                      const float* __restrict__ WhE, const float* __restrict__ bhE,
                      const float* __restrict__ b1,
                      __bf16* __restrict__ WyZR, __bf16* __restrict__ WyH,
                      __bf16* __restrict__ Wy1) {
  int idx = blockIdx.x * blockDim.x + threadIdx.x;
  const float* Weff; const float* beff; __bf16* out; int Nout, loc;
  if (idx < 1024 * 16) { Weff = WzrE; beff = bzrE; out = WyZR; Nout = 1024; loc = idx; }
  else if (idx < (1024 + 512) * 16) { Weff = WhE; beff = bhE; out = WyH; Nout = 512; loc = idx - 1024 * 16; }
  else if (idx < (1024 + 512 + 256) * 16) { Weff = nullptr; beff = b1; out = Wy1; Nout = 256; loc = idx - (1024 + 512) * 16; }
  else return;
  int n = loc >> 4, k = loc & 15;
  float v = 0.f;
  if (k < 4) v = Weff ? Weff[k * Nout + n] : 0.f;
  else if (k == 4) v = beff[n];
  out[(size_t)(n >> 7) * 2048 + (size_t)(n & 127) * 16 + k] = (__bf16)v;
}

__global__ void k_yat0(const float* __restrict__ Y,
                       const float* __restrict__ WzrE, const float* __restrict__ bzrE,
                       const float* __restrict__ WhE, const float* __restrict__ bhE,
                       __bf16* __restrict__ Ya, __bf16* __restrict__ H1, int n) {
  int idx = blockIdx.x * blockDim.x + threadIdx.x;
  int nt0 = n * 512;
  if (idx < nt0) {
    int i = idx >> 9, c = idx & 511;
    float y0 = Y[(size_t)i * NF + 0], y1 = Y[(size_t)i * NF + 12];
    float y2 = Y[(size_t)i * NF + 24], y3 = Y[(size_t)i * NF + 36];
    float pz = bzrE[c] + y0 * WzrE[c] + y1 * WzrE[1024 + c] +
               y2 * WzrE[2048 + c] + y3 * WzrE[3072 + c];
    float ph = bhE[c] + y0 * WhE[c] + y1 * WhE[512 + c] +
               y2 * WhE[1024 + c] + y3 * WhE[1536 + c];
    float z = 1.f / (1.f + expf(-pz));
    H1[idx] = (__bf16)((1.f - z) * tanhf(ph));
  } else {
    int r = idx - nt0;
    if (r >= TT * n * 16) return;
    int t = r / (n * 16);
    int loc = r % (n * 16);
    int nn = loc >> 4, k = loc & 15;
    float v = 0.f;
    if (k < 4) v = Y[(size_t)nn * NF + k * TT + t];
    else if (k == 4) v = 1.f;
    Ya[r] = (__bf16)v;
  }
}

// ---------------- MFMA GEMM: 128x128 tile, 512 threads / 8 waves, 32x32x16 ----------------
// R20: R15 pipeline (counted-vmcnt 3-buffer, 8-quad swizzle, XCD row-chunk map) with
// doubled tile: 8x MFMA per barrier-iteration (32 vs 4), 2 loads/thread/stage (vs 3),
// acc register count unchanged per thread. LDS 56 KB -> 2 blocks/CU, 16 waves/CU.
template <int MODE>
__global__ __launch_bounds__(512, 4) void k_mm(
    const __bf16* __restrict__ Agm, const __bf16* __restrict__ Bp,
    const __bf16* __restrict__ Hc, const __bf16* __restrict__ Zbf,
    const __bf16* __restrict__ Ay, const __bf16* __restrict__ Wy,
    float* __restrict__ Ofp, __bf16* __restrict__ Obf, __bf16* __restrict__ ObfR,
    int M, int RB) {
  constexpr int BUFS = 8192;  // elems per LDS k-buffer: A 4096 + B 4096
  // 3 k-buffers (24576) + Ay 2048 @24576 + Wy 2048 @26624 = 28672 elems = 56 KB
  __shared__ __bf16 smem[28672];
  constexpr int AYOFF = 24576, WYOFF = 26624;

  const int RBX = (RB + 7) >> 3;  // rowblks per XCD chunk
  int xcd = blockIdx.x & 7;
  int idx = blockIdx.x >> 3;
  int rowblk = xcd * RBX + idx % RBX;
  int colblk = idx / RBX;
  if (rowblk >= RB) return;

  const int row0 = rowblk * 128;
  const int tid = threadIdx.x;
  const int lane = tid & 63, w = tid >> 6;
  const int wr = (w >> 1) * 32, wc = (w & 1) * 64;
  const int l31 = lane & 31, lh = lane >> 5;

  // staging: thread tid owns LDS elems [tid*8, tid*8+8) of the A and B regions.
  // A source pre-swizzled so the linear LDS write realizes chunk^((row>>1)&3).
  const int ar = tid >> 2, ac = tid & 3;
  const __bf16* At = Agm + (size_t)(row0 + ar) * 512 + ((ac ^ ((ar >> 1) & 3)) << 3);
  const __bf16* Bt = Bp + (size_t)colblk * (128 * 512);

  v16f acc[2];
#pragma unroll
  for (int j = 0; j < 2; j++)
#pragma unroll
    for (int q = 0; q < 16; q++) acc[j][q] = 0.f;

  auto stage = [&](int buf, int kt) {
    __bf16* base = smem + buf * BUFS;
    gld16(At + kt * 32, base + w * 512);                        // A 128x32 swizzled
    gld16(Bt + (size_t)kt * 4096 + (size_t)tid * 8, base + 4096 + w * 512);  // B 128x32
  };
  // Y-tiles: Ay 128x16 + Wy 128x16, staged by waves 0-3 (tid<256), linear 16-wide
  auto stageY = [&]() {
    if (tid < 256) {
      gld16(Ay + (size_t)(row0 + (tid >> 1)) * 16 + (tid & 1) * 8, smem + AYOFF + w * 512);
      gld16(Wy + (size_t)colblk * 2048 + (size_t)tid * 8, smem + WYOFF + w * 512);
    }
  };
  auto compute = [&](int buf) {
    const __bf16* base = smem + buf * BUFS;
    __builtin_amdgcn_s_setprio(1);
#pragma unroll
    for (int ks = 0; ks < 2; ks++) {
      int kc = ks * 2 + lh;
      int fr = wr + l31;
      v8bf a = *(const v8bf*)&base[fr * 32 + ((kc ^ ((fr >> 1) & 3)) << 3)];
#pragma unroll
      for (int ni = 0; ni < 2; ni++) {
        int fc = wc + ni * 32 + l31;
        v8bf b = *(const v8bf*)&base[4096 + fc * 32 + ((kc ^ ((fc >> 1) & 3)) << 3)];
        acc[ni] = __builtin_amdgcn_mfma_f32_32x32x16_bf16(a, b, acc[ni], 0, 0, 0);
      }
    }
    __builtin_amdgcn_s_setprio(0);
  };
  auto computeY = [&]() {
    v8bf a = *(const v8bf*)&smem[AYOFF + (wr + l31) * 16 + lh * 8];
#pragma unroll
    for (int ni = 0; ni < 2; ni++) {
      v8bf b = *(const v8bf*)&smem[WYOFF + (wc + ni * 32 + l31) * 16 + lh * 8];
      acc[ni] = __builtin_amdgcn_mfma_f32_32x32x16_bf16(a, b, acc[ni], 0, 0, 0);
    }
  };

  // prologue: Y first (oldest; drained by the first counted wait), then bufs 0,1
  stageY();
  stage(0, 0);
  stage(1, 1);
#pragma unroll
  for (int kt = 0; kt < 16; kt++) {
    // wait: buf-kt (and, first iter, Y) landed; newest 2 (buf kt+1) may stay in flight
    if (kt < 15)
      asm volatile("s_waitcnt vmcnt(2) lgkmcnt(0)\n\ts_barrier" ::: "memory");
    else
      asm volatile("s_waitcnt vmcnt(0) lgkmcnt(0)\n\ts_barrier" ::: "memory");
    if (kt < 14) stage((kt + 2) % 3, kt + 2);  // overwrites buf (kt-1): safe
    compute(kt % 3);
  }
  computeY();  // Ay/Wy regions stable since the kt=0 barrier
  __syncthreads();  // before reusing smem as output stage

  // ---- epilogue. C layout (32x32): col=lane&31, row=(reg&3)+8*(reg>>2)+4*lh
  if constexpr (MODE == 2) {
#pragma unroll
    for (int ni = 0; ni < 2; ni++) {
      int cl = wc + ni * 32 + l31;
#pragma unroll
      for (int reg = 0; reg < 16; reg++) {
        int rg = row0 + wr + (reg & 3) + ((reg >> 2) << 3) + (lh << 2);
        if (rg >= M) continue;
        Ofp[(size_t)rg * 256 + colblk * 128 + cl] = fmaxf(acc[ni][reg], 0.f);
      }
    }
  } else if constexpr (MODE == 0) {
    // sigmoid -> LDS stage (128x128 bf16 = 32 KB, fits bufs 0-1), then wide stores
#pragma unroll
    for (int ni = 0; ni < 2; ni++) {
      int cl = wc + ni * 32 + l31;
#pragma unroll
      for (int reg = 0; reg < 16; reg++) {
        int lr = wr + (reg & 3) + ((reg >> 2) << 3) + (lh << 2);
        smem[lr * 128 + cl] = (__bf16)(1.f / (1.f + expf(-acc[ni][reg])));
      }
    }
    __syncthreads();
    int row = tid >> 2, seg = (tid & 3) * 32;
    int rg = row0 + row;
    if (rg < M) {
      int cof = (colblk & 3) * 128;
      if (colblk < 4) {  // z -> Obf, raw sigmoid
#pragma unroll
        for (int q = 0; q < 4; q++) {
          uint4 v = *(const uint4*)&smem[row * 128 + seg + q * 8];
          *(uint4*)(Obf + (size_t)rg * 512 + cof + seg + q * 8) = v;
        }
      } else {  // r -> ObfR, fused r*H (Agm holds H for these rows)
#pragma unroll
        for (int q = 0; q < 4; q++) {
          v8bf r8 = *(const v8bf*)&smem[row * 128 + seg + q * 8];
          v8bf h8 = *(const v8bf*)(Agm + (size_t)rg * 512 + cof + seg + q * 8);
          v8bf o;
#pragma unroll
          for (int j = 0; j < 8; j++) o[j] = (__bf16)((float)r8[j] * (float)h8[j]);
          *(v8bf*)(ObfR + (size_t)rg * 512 + cof + seg + q * 8) = o;
        }
      }
    }
  } else {  // MODE 1: four 32-row passes; fp32 ht region = 32x128 = 16 KB
    float* sF = (float*)smem;
#pragma unroll
    for (int h = 0; h < 4; h++) {
      if ((w >> 1) == h) {
#pragma unroll
        for (int ni = 0; ni < 2; ni++) {
          int cl = wc + ni * 32 + l31;
#pragma unroll
          for (int reg = 0; reg < 16; reg++) {
            int lr = (reg & 3) + ((reg >> 2) << 3) + (lh << 2);  // 0..31 local
            sF[lr * 128 + cl] = tanhf(acc[ni][reg]);
          }
        }
      }
      __syncthreads();
      int row = tid >> 4, seg = (tid & 15) * 8;
      int rg = row0 + h * 32 + row;
      if (rg < M) {
        int cg0 = colblk * 128 + seg;
        v8bf z8 = *(const v8bf*)(Zbf + (size_t)rg * 512 + cg0);
        v8bf h8 = *(const v8bf*)(Hc + (size_t)rg * 512 + cg0);
        v8bf o;
#pragma unroll
        for (int j = 0; j < 8; j++) {
          float z = (float)z8[j];
          float ht = sF[row * 128 + seg + j];
          o[j] = (__bf16)(z * (float)h8[j] + (1.f - z) * ht);
        }
        *(v8bf*)(Obf + (size_t)rg * 512 + cg0) = o;
      }
      if (h < 3) __syncthreads();  // protect sF before next group's writes
    }
  }
}

// acc[i,c] = sum_t probs[t] * hist[t+1][i,c];  accRelu = bf16(relu(acc))
__global__ void k_acc(const __bf16* __restrict__ hist, const float* __restrict__ probs,
                      float* __restrict__ acc, __bf16* __restrict__ accRelu, int n) {
  int idx = blockIdx.x * blockDim.x + threadIdx.x;
  if (idx >= n * 64) return;
  size_t off = (size_t)idx * 8;
  size_t S = (size_t)n * 512;
  float s[8] = {0, 0, 0, 0, 0, 0, 0, 0};
#pragma unroll
  for (int t = 0; t < TT; t++) {
    float p = probs[t];
    v8bf h = *(const v8bf*)(hist + (size_t)(t + 1) * S + off);
#pragma unroll
    for (int j = 0; j < 8; j++) s[j] = fmaf(p, (float)h[j], s[j]);
  }
  *(float4*)(acc + off) = make_float4(s[0], s[1], s[2], s[3]);
  *(float4*)(acc + off + 4) = make_float4(s[4], s[5], s[6], s[7]);
  v8bf rl;
#pragma unroll
  for (int j = 0; j < 8; j++) rl[j] = (__bf16)fmaxf(s[j], 0.f);
  *(v8bf*)(accRelu + off) = rl;
}

__global__ void k_head2(const float* __restrict__ T1, const float* __restrict__ W2,
                        const float* __restrict__ b2, float* __restrict__ out0, int M) {
  int idx = blockIdx.x * blockDim.x + threadIdx.x;
  if (idx >= M * 12) return;
  int i = idx / 12, c = idx % 12;
  const float* tr = T1 + (size_t)i * 256;
  float s = b2[c];
  for (int k = 0; k < 256; k++) s = fmaf(tr[k], W2[k * 12 + c], s);
  out0[idx] = s;
}

// ---------------- launch ----------------

extern "C" void kernel_launch(void* const* d_in, const int* in_sizes, int n_in,
                              void* d_out, int out_size, void* d_ws, size_t ws_size,
                              hipStream_t stream) {
  const float* x   = (const float*)d_in[0];
  const int*   ei  = (const int*)d_in[1];
  const float* ea  = (const float*)d_in[2];
  const float* att = (const float*)d_in[3];
  const float* Wzg = (const float*)d_in[4];  const float* bzg = (const float*)d_in[5];
  const float* Wzl = (const float*)d_in[6];  const float* bzl = (const float*)d_in[7];
  const float* Wrg = (const float*)d_in[8];  const float* brg = (const float*)d_in[9];
  const float* Wrl = (const float*)d_in[10]; const float* brl = (const float*)d_in[11];
  const float* Whg = (const float*)d_in[12]; const float* bhg = (const float*)d_in[13];
  const float* Whl = (const float*)d_in[14]; const float* bhl = (const float*)d_in[15];
  const float* W1  = (const float*)d_in[16]; const float* b1  = (const float*)d_in[17];
  const float* W2  = (const float*)d_in[18]; const float* b2  = (const float*)d_in[19];

  const int N = in_sizes[0] / NF;
  const int E = in_sizes[1] / 2;
  const int* srcI = ei;
  const int* dstI = ei + E;

  float* out0 = (float*)d_out;                   // [N,12]
  float* accO = (float*)d_out + (size_t)N * 12;  // [N,512] = H_accum (output 1)

  char* wp = (char*)d_ws;
  auto carve = [&](size_t bytes) -> void* {
    void* p = (void*)wp;
    wp += (bytes + 255) & ~(size_t)255;
    return p;
  };
  float*  deg     = (float*)carve((size_t)N * 4);
  float*  dinv    = (float*)carve((size_t)N * 4);
  float*  probs   = (float*)carve(64);
  float*  Y       = (float*)carve((size_t)N * NF * 4);
  __bf16* WzrP    = (__bf16*)carve((size_t)1024 * 512 * 2);
  __bf16* WhP     = (__bf16*)carve((size_t)512 * 512 * 2);
  __bf16* W1P     = (__bf16*)carve((size_t)256 * 512 * 2);
  float*  Wzr_eff = (float*)carve((size_t)4 * 1024 * 4);
  float*  bzr_eff = (float*)carve((size_t)1024 * 4);
  float*  Wh_eff  = (float*)carve((size_t)4 * 512 * 4);
  float*  bh_eff  = (float*)carve((size_t)512 * 4);
  __bf16* hist    = (__bf16*)carve((size_t)(TT + 1) * N * 512 * 2);  // H_0..H_12 bf16
  __bf16* Zbf     = (__bf16*)carve((size_t)N * 512 * 2);
  __bf16* Rbf     = (__bf16*)carve((size_t)N * 512 * 2);  // holds r*H
  __bf16* accRelu = (__bf16*)carve((size_t)N * 512 * 2);
  float*  T1      = (float*)carve((size_t)N * 256 * 4);
  __bf16* Ya      = (__bf16*)carve((size_t)TT * N * 16 * 2);
  __bf16* WyZR    = (__bf16*)carve((size_t)1024 * 16 * 2);
  __bf16* WyH     = (__bf16*)carve((size_t)512 * 16 * 2);
  __bf16* Wy1     = (__bf16*)carve((size_t)256 * 16 * 2);
  int*    cnt     = (int*)carve((size_t)2 * N * 4);  // cnt[N] + fill[N] contiguous
  int*    fill    = cnt + N;
  int*    offs    = (int*)carve((size_t)(N + 1) * 4);
  int*    pscan   = (int*)carve((size_t)N * 4);
  int*    bsum    = (int*)carve(256);
  int*    bpre    = (int*)carve(256);
  int*    csrc    = (int*)carve((size_t)E * 4);
  float*  cw      = (float*)carve((size_t)E * 4);
  (void)carve(512 * 1024);  // tail pad: OOB tile reads stay inside ws
  (void)ws_size; (void)n_in; (void)out_size;

  const int TPB = 256;
  auto cdiv = [](int a, int b) { return (a + b - 1) / b; };
  const size_t S = (size_t)N * 512;

  // degree + CSR counts
  k_init<<<cdiv(N, TPB), TPB, 0, stream>>>(deg, cnt, N);
  k_edge<<<cdiv(E, TPB), TPB, 0, stream>>>(dstI, ea, deg, cnt, E);

  // hierarchical scan (+dinv) -> offs; place; gather Y = Ahat @ X
  const int nb = cdiv(N, 256);
  k_scan1<<<nb, 256, 0, stream>>>(cnt, pscan, bsum, deg, dinv, N);
  k_scan2<<<1, 128, 0, stream>>>(bsum, bpre, nb, att, probs);
  k_scan3<<<cdiv(N, TPB), TPB, 0, stream>>>(pscan, bpre, offs, N, E);
  k_place<<<cdiv(E, TPB), TPB, 0, stream>>>(srcI, dstI, ea, offs, fill, csrc, cw, E);
  k_gather<<<cdiv(N * 12, TPB), TPB, 0, stream>>>(offs, csrc, cw, dinv, x, Y, N);

  // weight prep
  {
    dim3 gp(16, 8, 3);
    k_pack3<<<gp, 256, 0, stream>>>(Wzl, Wrl, Whl, W1, WzrP, WhP, W1P);
  }
  k_build_eff3<<<cdiv(3 * 5 * 512, TPB), TPB, 0, stream>>>(
      Wzg, Wzl, bzg, bzl, Wrg, Wrl, brg, brl, Whg, Whl, bhg, bhl,
      Wzr_eff, bzr_eff, Wh_eff, bh_eff);
  k_wy3<<<cdiv((1024 + 512 + 256) * 16, TPB), TPB, 0, stream>>>(
      Wzr_eff, bzr_eff, Wh_eff, bh_eff, b1, WyZR, WyH, Wy1);

  // merged Ya build + t=0 shortcut (H1 = (1-sigmoid(Yz)) * tanh(Yh))
  k_yat0<<<cdiv(N * 512 + TT * N * 16, TPB), TPB, 0, stream>>>(
      Y, Wzr_eff, bzr_eff, Wh_eff, bh_eff, Ya, hist + S, N);

  const int RB = cdiv(N, 128);         // 79 row blocks (128 rows each)
  const int RBX = cdiv(RB, 8);         // 10 rowblks per XCD chunk
  for (int t = 1; t < TT; t++) {
    const __bf16* Hbt = hist + (size_t)t * S;
    __bf16* Hbn = hist + (size_t)(t + 1) * S;
    const __bf16* Yat = Ya + (size_t)t * N * 16;
    // MODE0: A=H; writes z -> Zbf, r*H -> Rbf
    k_mm<0><<<8 * RBX * 8, 512, 0, stream>>>(Hbt, WzrP, nullptr, nullptr, Yat, WyZR,
                                             nullptr, Zbf, Rbf, N, RB);
    // MODE1: A=r*H (plain GEMM); H for the blend epilogue passed separately
    k_mm<1><<<8 * RBX * 4, 512, 0, stream>>>(Rbf, WhP, Hbt, Zbf, Yat, WyH,
                                             nullptr, Hbn, nullptr, N, RB);
  }

  // H_accum = sum_t p_t H_{t+1}; head
  k_acc<<<cdiv(N * 64, TPB), TPB, 0, stream>>>(hist, probs, accO, accRelu, N);
  k_mm<2><<<8 * RBX * 2, 512, 0, stream>>>(accRelu, W1P, nullptr, nullptr, Ya, Wy1,
                                           T1, nullptr, nullptr, N, RB);
  k_head2<<<cdiv(N * 12, TPB), TPB, 0, stream>>>(T1, W2, b2, out0, N);
}

// Round 11
// 671.786 us; speedup vs baseline: 2.3959x; 1.1398x over previous
//
#include <hip/hip_runtime.h>
#include <math.h>

// F=4, T=12, C=512, HID=256, OUT=12
#define NF 48
#define TT 12

typedef __bf16 v8bf __attribute__((ext_vector_type(8)));
typedef float v16f __attribute__((ext_vector_type(16)));

// direct global->LDS, 16B per lane; LDS dest must be wave-uniform (HW adds lane*16)
__device__ __forceinline__ void gld16(const void* g, void* l) {
  __builtin_amdgcn_global_load_lds(
      (const __attribute__((address_space(1))) void*)(uintptr_t)g,
      (__attribute__((address_space(3))) void*)(uintptr_t)l, 16, 0, 0);
}

// ---------------- small prep kernels ----------------

__global__ void k_init(float* __restrict__ deg, int* __restrict__ cnt, int n) {
  int i = blockIdx.x * blockDim.x + threadIdx.x;
  if (i < n) { deg[i] = 1.0f; cnt[i] = 0; cnt[n + i] = 0; }
}

__global__ void k_edge(const int* __restrict__ dst, const float* __restrict__ w,
                       float* __restrict__ deg, int* __restrict__ cnt, int e) {
  int i = blockIdx.x * blockDim.x + threadIdx.x;
  if (i < e) {
    int d = dst[i];
    atomicAdd(&deg[d], w[i]);
    atomicAdd(&cnt[d], 1);
  }
}

// ---------------- hierarchical scan (+ dinv fused) ----------------

__global__ void k_scan1(const int* __restrict__ cnt, int* __restrict__ pscan,
                        int* __restrict__ bsum, const float* __restrict__ deg,
                        float* __restrict__ dinv, int n) {
  __shared__ int s[256];
  int i = blockIdx.x * 256 + threadIdx.x;
  int v = (i < n) ? cnt[i] : 0;
  s[threadIdx.x] = v;
  __syncthreads();
  for (int off = 1; off < 256; off <<= 1) {
    int t = 0;
    if (threadIdx.x >= off) t = s[threadIdx.x - off];
    __syncthreads();
    s[threadIdx.x] += t;
    __syncthreads();
  }
  if (i < n) {
    pscan[i] = s[threadIdx.x] - v;
    dinv[i] = rsqrtf(fmaxf(deg[i], 1e-12f));
  }
  if (threadIdx.x == 255) bsum[blockIdx.x] = s[255];
}

__global__ void k_scan2(const int* __restrict__ bsum, int* __restrict__ bpre, int nb,
                        const float* __restrict__ att, float* __restrict__ probs) {
  if (blockIdx.x == 0 && threadIdx.x == 0) {
    int run = 0;
    for (int b = 0; b < nb; b++) { bpre[b] = run; run += bsum[b]; }
  }
  if (blockIdx.x == 0 && threadIdx.x == 64) {
    float m = -1e30f;
    for (int t = 0; t < TT; t++) m = fmaxf(m, att[t]);
    float e[TT], s = 0.f;
    for (int t = 0; t < TT; t++) { e[t] = expf(att[t] - m); s += e[t]; }
    for (int t = 0; t < TT; t++) probs[t] = e[t] / s;
  }
}

__global__ void k_scan3(const int* __restrict__ pscan, const int* __restrict__ bpre,
                        int* __restrict__ offs, int n, int e) {
  int i = blockIdx.x * blockDim.x + threadIdx.x;
  if (i < n) offs[i] = pscan[i] + bpre[i >> 8];
  if (i == 0) offs[n] = e;
}

__global__ void k_place(const int* __restrict__ src, const int* __restrict__ dst,
                        const float* __restrict__ w, const int* __restrict__ offs,
                        int* __restrict__ fill, int* __restrict__ csrc,
                        float* __restrict__ cw, int e) {
  int i = blockIdx.x * blockDim.x + threadIdx.x;
  if (i >= e) return;
  int d = dst[i];
  int p = offs[d] + atomicAdd(&fill[d], 1);
  csrc[p] = src[i];
  cw[p] = w[i];
}

__global__ void k_gather(const int* __restrict__ offs, const int* __restrict__ csrc,
                         const float* __restrict__ cw, const float* __restrict__ dinv,
                         const float* __restrict__ x, float* __restrict__ Y, int n) {
  int tg = blockIdx.x * blockDim.x + threadIdx.x;
  if (tg >= n * 12) return;
  int i = tg / 12, q = tg % 12;
  float di = dinv[i];
  const float4* x4 = (const float4*)x;
  float4 sv = x4[(size_t)i * 12 + q];
  float ax = di * sv.x, ay = di * sv.y, az = di * sv.z, aw = di * sv.w;
  int e1 = offs[i + 1];
  for (int e = offs[i]; e < e1; e++) {
    int s = csrc[e];
    float wv = cw[e] * dinv[s];
    float4 xv = x4[(size_t)s * 12 + q];
    ax = fmaf(wv, xv.x, ax); ay = fmaf(wv, xv.y, ay);
    az = fmaf(wv, xv.z, az); aw = fmaf(wv, xv.w, aw);
  }
  float4 o = make_float4(di * ax, di * ay, di * az, di * aw);
  ((float4*)Y)[(size_t)i * 12 + q] = o;
}

// ---------------- weight prep: LDS-tiled transpose into swizzled pack ----------------
// pack layout: [n/128][k/32][ row=n%128 ][ chunk(16B)^((row>>1)&3) ][ e ]
__device__ __forceinline__ size_t packIdx128(int n, int k) {
  int row = n & 127;
  int c = (k & 31) >> 3;
  return (size_t)(n >> 7) * (128 * 512) + (size_t)(k >> 5) * (128 * 32) +
         (size_t)row * 32 + (size_t)((c ^ ((row >> 1) & 3)) << 3) + (k & 7);
}

__global__ void k_pack3(const float* __restrict__ Wzl, const float* __restrict__ Wrl,
                        const float* __restrict__ Whl, const float* __restrict__ W1,
                        __bf16* __restrict__ WzrP, __bf16* __restrict__ WhP,
                        __bf16* __restrict__ W1P) {
  __shared__ __bf16 t[64][72];
  int modew = blockIdx.z;
  if (modew == 1 && blockIdx.x >= 8) return;
  if (modew == 2 && blockIdx.x >= 4) return;
  int n0 = blockIdx.x * 64, k0 = blockIdx.y * 64;
  __bf16* WT = (modew == 0) ? WzrP : (modew == 1) ? WhP : W1P;
#pragma unroll
  for (int p = 0; p < 4; p++) {
    int kk = p * 16 + (threadIdx.x >> 4);
    int nn = (threadIdx.x & 15) * 4;
    int n = n0 + nn, k = k0 + kk;
    float4 v;
    if (modew == 2) {
      v = *(const float4*)(W1 + (size_t)k * 256 + n);
    } else {
      const float* src = (modew == 1) ? Whl : Wzl;
      int nc = n;
      if (modew == 0 && n >= 512) { src = Wrl; nc = n - 512; }
      v = *(const float4*)(src + (size_t)(512 + k) * 512 + nc);
    }
    t[kk][nn + 0] = (__bf16)v.x; t[kk][nn + 1] = (__bf16)v.y;
    t[kk][nn + 2] = (__bf16)v.z; t[kk][nn + 3] = (__bf16)v.w;
  }
  __syncthreads();
#pragma unroll
  for (int u = 0; u < 2; u++) {
    int unit = threadIdx.x * 2 + u;
    int nl = unit >> 3, kg = unit & 7;
    v8bf o;
#pragma unroll
    for (int j = 0; j < 8; j++) o[j] = t[kg * 8 + j][nl];
    *(v8bf*)(WT + packIdx128(n0 + nl, k0 + kg * 8)) = o;
  }
}

__global__ void k_build_eff3(const float* __restrict__ Wzg, const float* __restrict__ Wzl,
                             const float* __restrict__ bzg, const float* __restrict__ bzl,
                             const float* __restrict__ Wrg, const float* __restrict__ Wrl,
                             const float* __restrict__ brg, const float* __restrict__ brl,
                             const float* __restrict__ Whg, const float* __restrict__ Whl,
                             const float* __restrict__ bhg, const float* __restrict__ bhl,
                             float* __restrict__ WzrE, float* __restrict__ bzrE,
                             float* __restrict__ WhE, float* __restrict__ bhE) {
  int idx = blockIdx.x * blockDim.x + threadIdx.x;
  if (idx >= 3 * 5 * 512) return;
  int seg = idx / 2560;
  int r = (idx % 2560) / 512, c = idx % 512;
  const float *Wg, *Wl, *bg, *bl;
  float *We, *be;
  int ostride, ooff;
  if (seg == 0) { Wg = Wzg; Wl = Wzl; bg = bzg; bl = bzl; We = WzrE; be = bzrE; ostride = 1024; ooff = 0; }
  else if (seg == 1) { Wg = Wrg; Wl = Wrl; bg = brg; bl = brl; We = WzrE; be = bzrE; ostride = 1024; ooff = 512; }
  else { Wg = Whg; Wl = Whl; bg = bhg; bl = bhl; We = WhE; be = bhE; ostride = 512; ooff = 0; }
  float s = 0.f;
  if (r < 4) {
    for (int k = 0; k < 512; k++) s += Wg[r * 512 + k] * Wl[k * 512 + c];
    We[r * ostride + ooff + c] = s;
  } else {
    for (int k = 0; k < 512; k++) s += bg[k] * Wl[k * 512 + c];
    be[ooff + c] = s + bl[c];
  }
}

__global__ void k_wy3(const float* __restrict__ WzrE, const float* __restrict__ bzrE,
                      const float* __restrict__ WhE, const float* __restrict__ bhE,
                      const float* __restrict__ b1,
                      __bf16* __restrict__ WyZR, __bf16* __restrict__ WyH,
                      __bf16* __restrict__ Wy1) {
  int idx = blockIdx.x * blockDim.x + threadIdx.x;
  const float* Weff; const float* beff; __bf16* out; int Nout, loc;
  if (idx < 1024 * 16) { Weff = WzrE; beff = bzrE; out = WyZR; Nout = 1024; loc = idx; }
  else if (idx < (1024 + 512) * 16) { Weff = WhE; beff = bhE; out = WyH; Nout = 512; loc = idx - 1024 * 16; }
  else if (idx < (1024 + 512 + 256) * 16) { Weff = nullptr; beff = b1; out = Wy1; Nout = 256; loc = idx - (1024 + 512) * 16; }
  else return;
  int n = loc >> 4, k = loc & 15;
  float v = 0.f;
  if (k < 4) v = Weff ? Weff[k * Nout + n] : 0.f;
  else if (k == 4) v = beff[n];
  out[(size_t)(n >> 7) * 2048 + (size_t)(n & 127) * 16 + k] = (__bf16)v;
}

__global__ void k_yat0(const float* __restrict__ Y,
                       const float* __restrict__ WzrE, const float* __restrict__ bzrE,
                       const float* __restrict__ WhE, const float* __restrict__ bhE,
                       __bf16* __restrict__ Ya, __bf16* __restrict__ H1, int n) {
  int idx = blockIdx.x * blockDim.x + threadIdx.x;
  int nt0 = n * 512;
  if (idx < nt0) {
    int i = idx >> 9, c = idx & 511;
    float y0 = Y[(size_t)i * NF + 0], y1 = Y[(size_t)i * NF + 12];
    float y2 = Y[(size_t)i * NF + 24], y3 = Y[(size_t)i * NF + 36];
    float pz = bzrE[c] + y0 * WzrE[c] + y1 * WzrE[1024 + c] +
               y2 * WzrE[2048 + c] + y3 * WzrE[3072 + c];
    float ph = bhE[c] + y0 * WhE[c] + y1 * WhE[512 + c] +
               y2 * WhE[1024 + c] + y3 * WhE[1536 + c];
    float z = 1.f / (1.f + expf(-pz));
    H1[idx] = (__bf16)((1.f - z) * tanhf(ph));
  } else {
    int r = idx - nt0;
    if (r >= TT * n * 16) return;
    int t = r / (n * 16);
    int loc = r % (n * 16);
    int nn = loc >> 4, k = loc & 15;
    float v = 0.f;
    if (k < 4) v = Y[(size_t)nn * NF + k * TT + t];
    else if (k == 4) v = 1.f;
    Ya[r] = (__bf16)v;
  }
}

// ---------------- MFMA GEMM: 64x128 tile, 32x32x16 ----------------
// R21: R3/R15 structure with the Y-tile moved from LDS to per-lane registers.
// LDS drops 42->36 KB -> 4 blocks/CU (was 3): 16 waves/CU in independent 4-wave
// barrier groups (R6 lesson: small barrier groups + occupancy beat big tiles).
// Y reg loads sit in the prologue; at iter kt's wait the newest-3 outstanding
// loads are always stage(kt+1)'s, so the counted vmcnt(3) invariant holds.
template <int MODE>
__global__ __launch_bounds__(256, 4) void k_mm(
    const __bf16* __restrict__ Agm, const __bf16* __restrict__ Bp,
    const __bf16* __restrict__ Hc, const __bf16* __restrict__ Zbf,
    const __bf16* __restrict__ Ay, const __bf16* __restrict__ Wy,
    float* __restrict__ Ofp, __bf16* __restrict__ Obf, __bf16* __restrict__ ObfR,
    int M, int RB) {
  constexpr int BUFS = 6144;  // elems per LDS k-buffer: A 2048 + B 4096
  __shared__ __bf16 smem[18432];  // 3 k-buffers = 36 KB

  const int RBX = (RB + 7) >> 3;  // rowblks per XCD chunk
  int xcd = blockIdx.x & 7;
  int idx = blockIdx.x >> 3;
  int rowblk = xcd * RBX + idx % RBX;
  int colblk = idx / RBX;
  if (rowblk >= RB) return;

  const int row0 = rowblk * 64;
  const int tid = threadIdx.x;
  const int lane = tid & 63, w = tid >> 6;
  const int wr = (w >> 1) * 32, wc = (w & 1) * 64;
  const int l31 = lane & 31, lh = lane >> 5;

  // staging geometry: thread tid owns LDS elems [tid*8, tid*8+8) of each region.
  // A source pre-swizzled so the linear LDS write realizes chunk^((row>>1)&3).
  const int ar = tid >> 2, ac = tid & 3;
  const __bf16* At = Agm + (size_t)(row0 + ar) * 512 + ((ac ^ ((ar >> 1) & 3)) << 3);
  const __bf16* Bt = Bp + (size_t)colblk * (128 * 512);

  v16f acc[2];
#pragma unroll
  for (int j = 0; j < 2; j++)
#pragma unroll
    for (int q = 0; q < 16; q++) acc[j][q] = 0.f;

  auto stage = [&](int buf, int kt) {
    __bf16* base = smem + buf * BUFS;
    gld16(At + kt * 32, base + w * 512);                 // A 64x32 swizzled
    const __bf16* bs = Bt + (size_t)kt * 4096 + (size_t)tid * 8;
    gld16(bs, base + 2048 + w * 512);                    // B rows 0..63
    gld16(bs + 2048, base + 4096 + w * 512);             // B rows 64..127
  };
  auto compute = [&](int buf) {
    const __bf16* base = smem + buf * BUFS;
    __builtin_amdgcn_s_setprio(1);
#pragma unroll
    for (int ks = 0; ks < 2; ks++) {
      int kc = ks * 2 + lh;
      int fr = wr + l31;
      v8bf a = *(const v8bf*)&base[fr * 32 + ((kc ^ ((fr >> 1) & 3)) << 3)];
#pragma unroll
      for (int ni = 0; ni < 2; ni++) {
        int fc = wc + ni * 32 + l31;
        v8bf b = *(const v8bf*)&base[2048 + fc * 32 + ((kc ^ ((fc >> 1) & 3)) << 3)];
        acc[ni] = __builtin_amdgcn_mfma_f32_32x32x16_bf16(a, b, acc[ni], 0, 0, 0);
      }
    }
    __builtin_amdgcn_s_setprio(0);
  };

  // prologue: per-lane Y-fragment register loads (L2-hot; consumed after the
  // final vmcnt(0) drain) + first two k-buffer stages
  v8bf ya = *(const v8bf*)(Ay + (size_t)(row0 + wr + l31) * 16 + lh * 8);
  v8bf yb0 = *(const v8bf*)(Wy + (size_t)colblk * 2048 + (size_t)(wc + l31) * 16 + lh * 8);
  v8bf yb1 = *(const v8bf*)(Wy + (size_t)colblk * 2048 + (size_t)(wc + 32 + l31) * 16 + lh * 8);
  stage(0, 0);
  stage(1, 1);
#pragma unroll
  for (int kt = 0; kt < 16; kt++) {
    // wait: this wave's buf-kt loads landed (newest 3 = buf kt+1 may fly);
    // barrier: all waves' buf-kt writes landed AND all done reading buf (kt-1)
    if (kt < 15)
      asm volatile("s_waitcnt vmcnt(3) lgkmcnt(0)\n\ts_barrier" ::: "memory");
    else
      asm volatile("s_waitcnt vmcnt(0) lgkmcnt(0)\n\ts_barrier" ::: "memory");
    if (kt < 14) stage((kt + 2) % 3, kt + 2);  // overwrites buf (kt-1): safe
    compute(kt % 3);
  }
  // Y-term: K extension by 16 from registers (drained by the kt=15 vmcnt(0))
  acc[0] = __builtin_amdgcn_mfma_f32_32x32x16_bf16(ya, yb0, acc[0], 0, 0, 0);
  acc[1] = __builtin_amdgcn_mfma_f32_32x32x16_bf16(ya, yb1, acc[1], 0, 0, 0);
  __syncthreads();  // before reusing smem as output stage

  // ---- epilogue. C layout (32x32): col=lane&31, row=(reg&3)+8*(reg>>2)+4*lh
  if constexpr (MODE == 2) {
#pragma unroll
    for (int ni = 0; ni < 2; ni++) {
      int cl = wc + ni * 32 + l31;
#pragma unroll
      for (int reg = 0; reg < 16; reg++) {
        int rg = row0 + wr + (reg & 3) + ((reg >> 2) << 3) + (lh << 2);
        if (rg >= M) continue;
        Ofp[(size_t)rg * 256 + colblk * 128 + cl] = fmaxf(acc[ni][reg], 0.f);
      }
    }
  } else if constexpr (MODE == 0) {
#pragma unroll
    for (int ni = 0; ni < 2; ni++) {
      int cl = wc + ni * 32 + l31;
#pragma unroll
      for (int reg = 0; reg < 16; reg++) {
        int lr = wr + (reg & 3) + ((reg >> 2) << 3) + (lh << 2);
        smem[lr * 128 + cl] = (__bf16)(1.f / (1.f + expf(-acc[ni][reg])));
      }
    }
    __syncthreads();
    int row = tid >> 2, seg = (tid & 3) * 32;
    int rg = row0 + row;
    if (rg < M) {
      int cof = (colblk & 3) * 128;
      if (colblk < 4) {  // z -> Obf, raw sigmoid
#pragma unroll
        for (int q = 0; q < 4; q++) {
          uint4 v = *(const uint4*)&smem[row * 128 + seg + q * 8];
          *(uint4*)(Obf + (size_t)rg * 512 + cof + seg + q * 8) = v;
        }
      } else {  // r -> ObfR, fused r*H (Agm holds H for these rows)
#pragma unroll
        for (int q = 0; q < 4; q++) {
          v8bf r8 = *(const v8bf*)&smem[row * 128 + seg + q * 8];
          v8bf h8 = *(const v8bf*)(Agm + (size_t)rg * 512 + cof + seg + q * 8);
          v8bf o;
#pragma unroll
          for (int j = 0; j < 8; j++) o[j] = (__bf16)((float)r8[j] * (float)h8[j]);
          *(v8bf*)(ObfR + (size_t)rg * 512 + cof + seg + q * 8) = o;
        }
      }
    }
  } else {  // MODE 1: two 32-row passes; fp32 ht region = 32x128 = 16 KB
    float* sF = (float*)smem;
#pragma unroll
    for (int h = 0; h < 2; h++) {
      if ((w >> 1) == h) {
#pragma unroll
        for (int ni = 0; ni < 2; ni++) {
          int cl = wc + ni * 32 + l31;
#pragma unroll
          for (int reg = 0; reg < 16; reg++) {
            int lr = (reg & 3) + ((reg >> 2) << 3) + (lh << 2);  // 0..31 local
            sF[lr * 128 + cl] = tanhf(acc[ni][reg]);
          }
        }
      }
      __syncthreads();
      int row = tid >> 3, seg = (tid & 7) * 16;
      int rg = row0 + h * 32 + row;
      if (rg < M) {
        int cg0 = colblk * 128 + seg;
#pragma unroll
        for (int q = 0; q < 2; q++) {
          v8bf z8 = *(const v8bf*)(Zbf + (size_t)rg * 512 + cg0 + q * 8);
          v8bf h8 = *(const v8bf*)(Hc + (size_t)rg * 512 + cg0 + q * 8);
          v8bf o;
#pragma unroll
          for (int j = 0; j < 8; j++) {
            float z = (float)z8[j];
            float ht = sF[row * 128 + seg + q * 8 + j];
            o[j] = (__bf16)(z * (float)h8[j] + (1.f - z) * ht);
          }
          *(v8bf*)(Obf + (size_t)rg * 512 + cg0 + q * 8) = o;
        }
      }
      if (h == 0) __syncthreads();  // protect sF before second-half writes
    }
  }
}

// acc[i,c] = sum_t probs[t] * hist[t+1][i,c];  accRelu = bf16(relu(acc))
__global__ void k_acc(const __bf16* __restrict__ hist, const float* __restrict__ probs,
                      float* __restrict__ acc, __bf16* __restrict__ accRelu, int n) {
  int idx = blockIdx.x * blockDim.x + threadIdx.x;
  if (idx >= n * 64) return;
  size_t off = (size_t)idx * 8;
  size_t S = (size_t)n * 512;
  float s[8] = {0, 0, 0, 0, 0, 0, 0, 0};
#pragma unroll
  for (int t = 0; t < TT; t++) {
    float p = probs[t];
    v8bf h = *(const v8bf*)(hist + (size_t)(t + 1) * S + off);
#pragma unroll
    for (int j = 0; j < 8; j++) s[j] = fmaf(p, (float)h[j], s[j]);
  }
  *(float4*)(acc + off) = make_float4(s[0], s[1], s[2], s[3]);
  *(float4*)(acc + off + 4) = make_float4(s[4], s[5], s[6], s[7]);
  v8bf rl;
#pragma unroll
  for (int j = 0; j < 8; j++) rl[j] = (__bf16)fmaxf(s[j], 0.f);
  *(v8bf*)(accRelu + off) = rl;
}

__global__ void k_head2(const float* __restrict__ T1, const float* __restrict__ W2,
                        const float* __restrict__ b2, float* __restrict__ out0, int M) {
  int idx = blockIdx.x * blockDim.x + threadIdx.x;
  if (idx >= M * 12) return;
  int i = idx / 12, c = idx % 12;
  const float* tr = T1 + (size_t)i * 256;
  float s = b2[c];
  for (int k = 0; k < 256; k++) s = fmaf(tr[k], W2[k * 12 + c], s);
  out0[idx] = s;
}

// ---------------- launch ----------------

extern "C" void kernel_launch(void* const* d_in, const int* in_sizes, int n_in,
                              void* d_out, int out_size, void* d_ws, size_t ws_size,
                              hipStream_t stream) {
  const float* x   = (const float*)d_in[0];
  const int*   ei  = (const int*)d_in[1];
  const float* ea  = (const float*)d_in[2];
  const float* att = (const float*)d_in[3];
  const float* Wzg = (const float*)d_in[4];  const float* bzg = (const float*)d_in[5];
  const float* Wzl = (const float*)d_in[6];  const float* bzl = (const float*)d_in[7];
  const float* Wrg = (const float*)d_in[8];  const float* brg = (const float*)d_in[9];
  const float* Wrl = (const float*)d_in[10]; const float* brl = (const float*)d_in[11];
  const float* Whg = (const float*)d_in[12]; const float* bhg = (const float*)d_in[13];
  const float* Whl = (const float*)d_in[14]; const float* bhl = (const float*)d_in[15];
  const float* W1  = (const float*)d_in[16]; const float* b1  = (const float*)d_in[17];
  const float* W2  = (const float*)d_in[18]; const float* b2  = (const float*)d_in[19];

  const int N = in_sizes[0] / NF;
  const int E = in_sizes[1] / 2;
  const int* srcI = ei;
  const int* dstI = ei + E;

  float* out0 = (float*)d_out;                   // [N,12]
  float* accO = (float*)d_out + (size_t)N * 12;  // [N,512] = H_accum (output 1)

  char* wp = (char*)d_ws;
  auto carve = [&](size_t bytes) -> void* {
    void* p = (void*)wp;
    wp += (bytes + 255) & ~(size_t)255;
    return p;
  };
  float*  deg     = (float*)carve((size_t)N * 4);
  float*  dinv    = (float*)carve((size_t)N * 4);
  float*  probs   = (float*)carve(64);
  float*  Y       = (float*)carve((size_t)N * NF * 4);
  __bf16* WzrP    = (__bf16*)carve((size_t)1024 * 512 * 2);
  __bf16* WhP     = (__bf16*)carve((size_t)512 * 512 * 2);
  __bf16* W1P     = (__bf16*)carve((size_t)256 * 512 * 2);
  float*  Wzr_eff = (float*)carve((size_t)4 * 1024 * 4);
  float*  bzr_eff = (float*)carve((size_t)1024 * 4);
  float*  Wh_eff  = (float*)carve((size_t)4 * 512 * 4);
  float*  bh_eff  = (float*)carve((size_t)512 * 4);
  __bf16* hist    = (__bf16*)carve((size_t)(TT + 1) * N * 512 * 2);  // H_0..H_12 bf16
  __bf16* Zbf     = (__bf16*)carve((size_t)N * 512 * 2);
  __bf16* Rbf     = (__bf16*)carve((size_t)N * 512 * 2);  // holds r*H
  __bf16* accRelu = (__bf16*)carve((size_t)N * 512 * 2);
  float*  T1      = (float*)carve((size_t)N * 256 * 4);
  __bf16* Ya      = (__bf16*)carve((size_t)TT * N * 16 * 2);
  __bf16* WyZR    = (__bf16*)carve((size_t)1024 * 16 * 2);
  __bf16* WyH     = (__bf16*)carve((size_t)512 * 16 * 2);
  __bf16* Wy1     = (__bf16*)carve((size_t)256 * 16 * 2);
  int*    cnt     = (int*)carve((size_t)2 * N * 4);  // cnt[N] + fill[N] contiguous
  int*    fill    = cnt + N;
  int*    offs    = (int*)carve((size_t)(N + 1) * 4);
  int*    pscan   = (int*)carve((size_t)N * 4);
  int*    bsum    = (int*)carve(256);
  int*    bpre    = (int*)carve(256);
  int*    csrc    = (int*)carve((size_t)E * 4);
  float*  cw      = (float*)carve((size_t)E * 4);
  (void)carve(512 * 1024);  // tail pad: OOB tile reads stay inside ws
  (void)ws_size; (void)n_in; (void)out_size;

  const int TPB = 256;
  auto cdiv = [](int a, int b) { return (a + b - 1) / b; };
  const size_t S = (size_t)N * 512;

  // degree + CSR counts
  k_init<<<cdiv(N, TPB), TPB, 0, stream>>>(deg, cnt, N);
  k_edge<<<cdiv(E, TPB), TPB, 0, stream>>>(dstI, ea, deg, cnt, E);

  // hierarchical scan (+dinv) -> offs; place; gather Y = Ahat @ X
  const int nb = cdiv(N, 256);
  k_scan1<<<nb, 256, 0, stream>>>(cnt, pscan, bsum, deg, dinv, N);
  k_scan2<<<1, 128, 0, stream>>>(bsum, bpre, nb, att, probs);
  k_scan3<<<cdiv(N, TPB), TPB, 0, stream>>>(pscan, bpre, offs, N, E);
  k_place<<<cdiv(E, TPB), TPB, 0, stream>>>(srcI, dstI, ea, offs, fill, csrc, cw, E);
  k_gather<<<cdiv(N * 12, TPB), TPB, 0, stream>>>(offs, csrc, cw, dinv, x, Y, N);

  // weight prep
  {
    dim3 gp(16, 8, 3);
    k_pack3<<<gp, 256, 0, stream>>>(Wzl, Wrl, Whl, W1, WzrP, WhP, W1P);
  }
  k_build_eff3<<<cdiv(3 * 5 * 512, TPB), TPB, 0, stream>>>(
      Wzg, Wzl, bzg, bzl, Wrg, Wrl, brg, brl, Whg, Whl, bhg, bhl,
      Wzr_eff, bzr_eff, Wh_eff, bh_eff);
  k_wy3<<<cdiv((1024 + 512 + 256) * 16, TPB), TPB, 0, stream>>>(
      Wzr_eff, bzr_eff, Wh_eff, bh_eff, b1, WyZR, WyH, Wy1);

  // merged Ya build + t=0 shortcut (H1 = (1-sigmoid(Yz)) * tanh(Yh))
  k_yat0<<<cdiv(N * 512 + TT * N * 16, TPB), TPB, 0, stream>>>(
      Y, Wzr_eff, bzr_eff, Wh_eff, bh_eff, Ya, hist + S, N);

  const int RB = cdiv(N, 64);          // 157 row blocks
  const int RBX = cdiv(RB, 8);         // 20 rowblks per XCD chunk
  for (int t = 1; t < TT; t++) {
    const __bf16* Hbt = hist + (size_t)t * S;
    __bf16* Hbn = hist + (size_t)(t + 1) * S;
    const __bf16* Yat = Ya + (size_t)t * N * 16;
    // MODE0: A=H; writes z -> Zbf, r*H -> Rbf
    k_mm<0><<<8 * RBX * 8, 256, 0, stream>>>(Hbt, WzrP, nullptr, nullptr, Yat, WyZR,
                                             nullptr, Zbf, Rbf, N, RB);
    // MODE1: A=r*H (plain GEMM); H for the blend epilogue passed separately
    k_mm<1><<<8 * RBX * 4, 256, 0, stream>>>(Rbf, WhP, Hbt, Zbf, Yat, WyH,
                                             nullptr, Hbn, nullptr, N, RB);
  }

  // H_accum = sum_t p_t H_{t+1}; head
  k_acc<<<cdiv(N * 64, TPB), TPB, 0, stream>>>(hist, probs, accO, accRelu, N);
  k_mm<2><<<8 * RBX * 2, 256, 0, stream>>>(accRelu, W1P, nullptr, nullptr, Ya, Wy1,
                                           T1, nullptr, nullptr, N, RB);
  k_head2<<<cdiv(N * 12, TPB), TPB, 0, stream>>>(T1, W2, b2, out0, N);
}